// Round 1
// baseline (508.591 us; speedup 1.0000x reference)
//
#include <hip/hip_runtime.h>

#define BB 64
#define TT 60
#define LL 49
#define HID 768
#define E2 1536
#define VOC 10000
#define BT (BB*TT)      // 3840
#define BL (BB*LL)      // 3136
#define NPAD_MLP 10112  // 79*128
#define NPAD_S 128

typedef __bf16 bf16x8 __attribute__((ext_vector_type(8)));
typedef float f32x4 __attribute__((ext_vector_type(4)));

__device__ __forceinline__ unsigned short f2bf(float f) {
  union { float f; unsigned int u; } v; v.f = f;
  unsigned int u = v.u;
  return (unsigned short)((u + 0x7fffu + ((u >> 16) & 1u)) >> 16);  // RNE
}
__device__ __forceinline__ float bf2f(unsigned short h) {
  union { unsigned int u; float f; } v; v.u = ((unsigned int)h) << 16;
  return v.f;
}
__device__ __forceinline__ float fast_tanh(float x) {
  // 1 - 2/(e^{2x}+1): overflow-safe (x->+inf => 1, -inf => -1), no NaN
  float e = __expf(2.f * x);
  return 1.f - 2.f / (e + 1.f);
}
__device__ __forceinline__ float fast_sigmoid(float x) {
  return 1.f / (1.f + __expf(-x));
}

// ---------------- converts (vectorized float4 -> 4x bf16) ----------------
__global__ void k_conv(const float* __restrict__ src, unsigned short* __restrict__ dst, int n4) {
  int i = blockIdx.x * blockDim.x + threadIdx.x;
  int stride = gridDim.x * blockDim.x;
  for (; i < n4; i += stride) {
    float4 v = ((const float4*)src)[i];
    ushort4 o;
    o.x = f2bf(v.x); o.y = f2bf(v.y); o.z = f2bf(v.z); o.w = f2bf(v.w);
    ((ushort4*)dst)[i] = o;
  }
}
// zero-pads rows [nrows, nrows_pad) ; k must be divisible by 4
__global__ void k_convpad(const float* __restrict__ src, unsigned short* __restrict__ dst,
                          int nrows, int k4, int nrows_pad) {
  int n4 = nrows_pad * k4;
  int i = blockIdx.x * blockDim.x + threadIdx.x;
  int stride = gridDim.x * blockDim.x;
  for (; i < n4; i += stride) {
    int row = i / k4;
    ushort4 o;
    if (row < nrows) {
      float4 v = ((const float4*)src)[i];
      o.x = f2bf(v.x); o.y = f2bf(v.y); o.z = f2bf(v.z); o.w = f2bf(v.w);
    } else { o.x = o.y = o.z = o.w = 0; }
    ((ushort4*)dst)[i] = o;
  }
}
// hiddens_t_1: shift by one timestep, t==0 -> zeros; HID/4 = 192 vec4 per row
__global__ void k_shift(const float* __restrict__ hid, unsigned short* __restrict__ dst, int n4) {
  int i = blockIdx.x * blockDim.x + threadIdx.x;
  int stride = gridDim.x * blockDim.x;
  for (; i < n4; i += stride) {
    int bt = i / (HID/4);
    int t = bt % TT;
    ushort4 o;
    if (t == 0) { o.x = o.y = o.z = o.w = 0; }
    else {
      float4 v = ((const float4*)hid)[i - (HID/4)];
      o.x = f2bf(v.x); o.y = f2bf(v.y); o.z = f2bf(v.z); o.w = f2bf(v.w);
    }
    ((ushort4*)dst)[i] = o;
  }
}

// ---------------- generic bf16 GEMM: C(MxNout) = A(MxK) * B(NxK)^T ----------------
// m97 structure: 128x128 tile, BK=32, 4 waves (2x2), each wave 4x4 16x16 MFMA tiles.
// A rows clamped to M-1 (stores guarded); B buffer must have >= gridDim.x*128 rows (zero-padded).
__global__ __launch_bounds__(256) void gemm_bt(
    const unsigned short* __restrict__ A,
    const unsigned short* __restrict__ Bw,
    float* __restrict__ C,
    int M, int Nout, int K,
    const float* __restrict__ bias)
{
  __shared__ __attribute__((aligned(16))) unsigned short As[128*32];
  __shared__ __attribute__((aligned(16))) unsigned short Bs[128*32];
  const int tid  = threadIdx.x;
  const int lane = tid & 63;
  const int wave = tid >> 6;
  const int m0 = blockIdx.y * 128;
  const int n0 = blockIdx.x * 128;
  const int wm = (wave >> 1) * 64;
  const int wn = (wave & 1) * 64;

  f32x4 acc[4][4];
#pragma unroll
  for (int i = 0; i < 4; ++i)
#pragma unroll
    for (int j = 0; j < 4; ++j) acc[i][j] = f32x4{0.f, 0.f, 0.f, 0.f};

  const int lrow = lane & 15;
  const int kb   = (lane >> 4) * 8;

  for (int k0 = 0; k0 < K; k0 += 32) {
    __syncthreads();  // previous iteration's ds_reads done before overwrite
#pragma unroll
    for (int p = 0; p < 2; ++p) {
      int slot = p * 256 + wave * 64 + lane;
      int row = slot >> 2, c8 = slot & 3;
      int ar = m0 + row; ar = ar < M ? ar : (M - 1);
      const unsigned short* asrc = A + (size_t)ar * K + k0 + c8 * 8;
      __builtin_amdgcn_global_load_lds(
          (const __attribute__((address_space(1))) void*)asrc,
          (__attribute__((address_space(3))) void*)&As[(p * 256 + wave * 64) * 8],
          16, 0, 0);
      const unsigned short* bsrc = Bw + (size_t)(n0 + row) * K + k0 + c8 * 8;
      __builtin_amdgcn_global_load_lds(
          (const __attribute__((address_space(1))) void*)bsrc,
          (__attribute__((address_space(3))) void*)&Bs[(p * 256 + wave * 64) * 8],
          16, 0, 0);
    }
    __syncthreads();  // compiler drains vmcnt before the barrier

    bf16x8 av[4], bv[4];
#pragma unroll
    for (int i = 0; i < 4; ++i)
      av[i] = *(const bf16x8*)&As[(wm + i * 16 + lrow) * 32 + kb];
#pragma unroll
    for (int j = 0; j < 4; ++j)
      bv[j] = *(const bf16x8*)&Bs[(wn + j * 16 + lrow) * 32 + kb];
#pragma unroll
    for (int i = 0; i < 4; ++i)
#pragma unroll
      for (int j = 0; j < 4; ++j)
        acc[i][j] = __builtin_amdgcn_mfma_f32_16x16x32_bf16(av[i], bv[j], acc[i][j], 0, 0, 0);
  }

  // C/D layout (m89/m91-verified): col = lane&15, row = (lane>>4)*4 + reg
  const int cr = (lane >> 4) * 4;
  const int cc = lane & 15;
#pragma unroll
  for (int i = 0; i < 4; ++i) {
    int row0 = m0 + wm + i * 16 + cr;
#pragma unroll
    for (int j = 0; j < 4; ++j) {
      int col = n0 + wn + j * 16 + cc;
      if (col < Nout) {
        float badd = bias ? bias[col] : 0.f;
#pragma unroll
        for (int r = 0; r < 4; ++r) {
          int row = row0 + r;
          if (row < M) C[(size_t)row * Nout + col] = acc[i][j][r] + badd;
        }
      }
    }
  }
}

// ---------------- E1: q[b,h] = mean_t xa[b,t,h]  (xa = XW cols 768..1535) ----------------
__global__ void k_qmean(const float* __restrict__ XW, float* __restrict__ q) {
  int b = blockIdx.x;
  for (int h = threadIdx.x; h < HID; h += blockDim.x) {
    float s = 0.f;
    for (int t = 0; t < TT; ++t) s += XW[(size_t)(b * TT + t) * E2 + HID + h];
    q[b * HID + h] = s * (1.f / 60.f);
  }
}

// ---------------- E2: s_t = sigmoid(xs + h_prev@W_sh^T) * tanh(cells) -> bf16 ----------------
__global__ void k_st(const float* __restrict__ XW, const float* __restrict__ HS,
                     const float* __restrict__ cells, unsigned short* __restrict__ stbf, int n) {
  int i = blockIdx.x * blockDim.x + threadIdx.x;
  int stride = gridDim.x * blockDim.x;
  for (; i < n; i += stride) {
    int bt = i / HID, h = i - bt * HID;
    float pre = XW[(size_t)bt * E2 + h] + HS[i];
    float v = fast_sigmoid(pre) * fast_tanh(cells[i]);
    stbf[i] = f2bf(v);
  }
}

// ---------------- E3: switch softmax + V = sw0*H + sw1*G ----------------
__global__ __launch_bounds__(256) void k_switch(
    const float* __restrict__ AH, const float* __restrict__ AG,
    const float* __restrict__ q, const float* __restrict__ wsw,
    const float* __restrict__ H, const float* __restrict__ G,
    unsigned short* __restrict__ Vbf, float* __restrict__ sw_out)
{
  int bl = blockIdx.x;
  int b = bl / LL;
  int tid = threadIdx.x;
  float aH = 0.f, aG = 0.f;
  for (int h = tid; h < HID; h += 256) {
    float qv = q[b * HID + h], w = wsw[h];
    aH += fast_tanh(AH[(size_t)bl * HID + h] + qv) * w;
    aG += fast_tanh(AG[(size_t)bl * HID + h] + qv) * w;
  }
#pragma unroll
  for (int off = 32; off > 0; off >>= 1) {
    aH += __shfl_down(aH, off);
    aG += __shfl_down(aG, off);
  }
  __shared__ float redH[4], redG[4];
  int lane = tid & 63, wave = tid >> 6;
  if (lane == 0) { redH[wave] = aH; redG[wave] = aG; }
  __syncthreads();
  float sH = redH[0] + redH[1] + redH[2] + redH[3];
  float sG = redG[0] + redG[1] + redG[2] + redG[3];
  float m = fmaxf(sH, sG);
  float e0 = __expf(sH - m), e1 = __expf(sG - m);
  float inv = 1.f / (e0 + e1);
  float sw0 = e0 * inv, sw1 = e1 * inv;
  if (tid == 0) { sw_out[bl * 2] = sw0; sw_out[bl * 2 + 1] = sw1; }
  for (int h = tid; h < HID; h += 256) {
    float v = sw0 * H[(size_t)bl * HID + h] + sw1 * G[(size_t)bl * HID + h];
    Vbf[(size_t)bl * HID + h] = f2bf(v);
  }
}

// ---------------- E4: z_t/z_s -> alpha/beta -> c_hat+hiddens (bf16) ----------------
// One block handles TG=4 timesteps of one batch so the 49x768 V panel is reused 4x.
__global__ __launch_bounds__(256) void k_attn(
    const float* __restrict__ PV, const float* __restrict__ PG,
    const float* __restrict__ SS, const float* __restrict__ wh,
    const unsigned short* __restrict__ stbf, const unsigned short* __restrict__ Vbf,
    const float* __restrict__ hiddens,
    float* __restrict__ alpha_out, float* __restrict__ beta_out,
    unsigned short* __restrict__ chh)
{
  const int TG = 4;
  int b  = blockIdx.x / (TT / TG);
  int t0 = (blockIdx.x % (TT / TG)) * TG;
  int tid = threadIdx.x;
  __shared__ float pg_s[TG][LL], wh_s[LL], zz[TG][LL + 1], alpha_s[TG][LL], beta_sh[TG];

  if (tid < LL) wh_s[tid] = wh[tid];
  if (tid < TG * LL) {
    int tt = tid / LL, k = tid - tt * LL;
    pg_s[tt][k] = PG[(size_t)(b * TT + t0 + tt) * 64 + k];
  }
  __syncthreads();

  if (tid < TG * (LL + 1)) {
    int tt = tid / (LL + 1), l = tid - tt * (LL + 1);
    const float* src = (l < LL) ? &PV[((size_t)b * LL + l) * 64]
                                : &SS[(size_t)(b * TT + t0 + tt) * 64];
    float acc = 0.f;
    for (int k = 0; k < LL; ++k) acc += fast_tanh(src[k] + pg_s[tt][k]) * wh_s[k];
    zz[tt][l] = acc;
  }
  __syncthreads();

  if (tid < TG) {
    int tt = tid, bt = b * TT + t0 + tt;
    float mx = -1e30f;
    for (int l = 0; l < LL; ++l) mx = fmaxf(mx, zz[tt][l]);
    float sum = 0.f;
    for (int l = 0; l < LL; ++l) { float e = __expf(zz[tt][l] - mx); alpha_s[tt][l] = e; sum += e; }
    float inv = 1.f / sum;
    for (int l = 0; l < LL; ++l) {
      alpha_s[tt][l] *= inv;
      alpha_out[(size_t)bt * LL + l] = alpha_s[tt][l];
    }
    float mx2 = fmaxf(mx, zz[tt][LL]);
    float s2 = 0.f;
    for (int l = 0; l <= LL; ++l) s2 += __expf(zz[tt][l] - mx2);
    float bet = __expf(zz[tt][LL] - mx2) / s2;
    beta_sh[tt] = bet;
    beta_out[bt] = bet;
  }
  __syncthreads();

  for (int h = tid; h < HID; h += 256) {
    float ct[TG] = {0.f, 0.f, 0.f, 0.f};
    for (int l = 0; l < LL; ++l) {
      float v = bf2f(Vbf[((size_t)b * LL + l) * HID + h]);
#pragma unroll
      for (int tt = 0; tt < TG; ++tt) ct[tt] += alpha_s[tt][l] * v;
    }
#pragma unroll
    for (int tt = 0; tt < TG; ++tt) {
      int bt = b * TT + t0 + tt;
      float bet = beta_sh[tt];
      float s = bf2f(stbf[(size_t)bt * HID + h]);
      float chat = bet * s + (1.f - bet) * ct[tt];
      chh[(size_t)bt * HID + h] = f2bf(chat + hiddens[(size_t)bt * HID + h]);
    }
  }
}

// ---------------- launcher ----------------
static inline int nblk(long n) {
  long g = (n + 255) / 256;
  if (g > 8192) g = 8192;
  return (int)g;
}

extern "C" void kernel_launch(void* const* d_in, const int* in_sizes, int n_in,
                              void* d_out, int out_size, void* d_ws, size_t ws_size,
                              hipStream_t stream)
{
  const float* x       = (const float*)d_in[0];
  const float* hiddens = (const float*)d_in[1];
  const float* cells   = (const float*)d_in[2];
  const float* G       = (const float*)d_in[3];
  const float* H       = (const float*)d_in[4];
  const float* W_sx    = (const float*)d_in[5];
  const float* W_sh    = (const float*)d_in[6];
  const float* W_ax    = (const float*)d_in[7];
  const float* W_ah    = (const float*)d_in[8];
  const float* W_ag    = (const float*)d_in[9];
  const float* w_sw    = (const float*)d_in[10];
  const float* Wv      = (const float*)d_in[11];
  const float* Wg      = (const float*)d_in[12];
  const float* Ws      = (const float*)d_in[13];
  const float* wh      = (const float*)d_in[14];
  const float* W_mlp   = (const float*)d_in[15];
  const float* b_mlp   = (const float*)d_in[16];

  float* scores = (float*)d_out;
  float* alpha  = scores + (size_t)BT * VOC;
  float* beta   = alpha + (size_t)BT * LL;
  float* swout  = beta + BT;

  char* wsp = (char*)d_ws;
  size_t off = 0;
  auto alloc = [&](size_t bytes) -> char* {
    char* p = wsp + off;
    off += (bytes + 255) & ~(size_t)255;
    return p;
  };

  // bf16 buffers
  unsigned short* xbf    = (unsigned short*)alloc((size_t)BT * E2 * 2);
  unsigned short* wsa    = (unsigned short*)alloc((size_t)E2 * E2 * 2);     // [W_sx; W_ax]
  unsigned short* hprev  = (unsigned short*)alloc((size_t)BT * HID * 2);
  unsigned short* wshb   = (unsigned short*)alloc((size_t)HID * HID * 2);
  unsigned short* wahb   = (unsigned short*)alloc((size_t)HID * HID * 2);
  unsigned short* wagb   = (unsigned short*)alloc((size_t)HID * HID * 2);
  unsigned short* Hbf    = (unsigned short*)alloc((size_t)BL * HID * 2);
  unsigned short* Gbf    = (unsigned short*)alloc((size_t)BL * HID * 2);
  unsigned short* hidbf  = (unsigned short*)alloc((size_t)BT * HID * 2);
  unsigned short* wvb    = (unsigned short*)alloc((size_t)NPAD_S * HID * 2);
  unsigned short* wgb    = (unsigned short*)alloc((size_t)NPAD_S * HID * 2);
  unsigned short* wsb    = (unsigned short*)alloc((size_t)NPAD_S * HID * 2);
  unsigned short* wmlpb  = (unsigned short*)alloc((size_t)NPAD_MLP * HID * 2);
  unsigned short* Vbf    = (unsigned short*)alloc((size_t)BL * HID * 2);
  unsigned short* stbf   = (unsigned short*)alloc((size_t)BT * HID * 2);
  unsigned short* chh    = (unsigned short*)alloc((size_t)BT * HID * 2);
  // fp32 buffers
  float* XW = (float*)alloc((size_t)BT * E2 * 4);
  float* HS = (float*)alloc((size_t)BT * HID * 4);
  float* AH = (float*)alloc((size_t)BL * HID * 4);
  float* AG = (float*)alloc((size_t)BL * HID * 4);
  float* qb = (float*)alloc((size_t)BB * HID * 4);
  float* PV = (float*)alloc((size_t)BL * 64 * 4);
  float* PG = (float*)alloc((size_t)BT * 64 * 4);
  float* SS = (float*)alloc((size_t)BT * 64 * 4);
  (void)ws_size; (void)in_sizes; (void)n_in; (void)out_size;

  // --- converts ---
  k_conv<<<nblk(HID * E2 / 4), 256, 0, stream>>>(W_sx, wsa, HID * E2 / 4);
  k_conv<<<nblk(HID * E2 / 4), 256, 0, stream>>>(W_ax, wsa + (size_t)HID * E2, HID * E2 / 4);
  k_conv<<<nblk((long)BT * E2 / 4), 256, 0, stream>>>(x, xbf, BT * E2 / 4);
  k_shift<<<nblk((long)BT * HID / 4), 256, 0, stream>>>(hiddens, hprev, BT * HID / 4);
  k_conv<<<nblk(HID * HID / 4), 256, 0, stream>>>(W_sh, wshb, HID * HID / 4);
  k_conv<<<nblk(HID * HID / 4), 256, 0, stream>>>(W_ah, wahb, HID * HID / 4);
  k_conv<<<nblk(HID * HID / 4), 256, 0, stream>>>(W_ag, wagb, HID * HID / 4);
  k_conv<<<nblk((long)BL * HID / 4), 256, 0, stream>>>(H, Hbf, BL * HID / 4);
  k_conv<<<nblk((long)BL * HID / 4), 256, 0, stream>>>(G, Gbf, BL * HID / 4);
  k_conv<<<nblk((long)BT * HID / 4), 256, 0, stream>>>(hiddens, hidbf, BT * HID / 4);
  k_convpad<<<nblk(NPAD_S * HID / 4), 256, 0, stream>>>(Wv, wvb, LL, HID / 4, NPAD_S);
  k_convpad<<<nblk(NPAD_S * HID / 4), 256, 0, stream>>>(Wg, wgb, LL, HID / 4, NPAD_S);
  k_convpad<<<nblk(NPAD_S * HID / 4), 256, 0, stream>>>(Ws, wsb, LL, HID / 4, NPAD_S);
  k_convpad<<<nblk((long)NPAD_MLP * HID / 4), 256, 0, stream>>>(W_mlp, wmlpb, VOC, HID / 4, NPAD_MLP);

  // --- big GEMMs ---
  gemm_bt<<<dim3(E2 / 128, BT / 128), 256, 0, stream>>>(xbf, wsa, XW, BT, E2, E2, nullptr);
  gemm_bt<<<dim3(HID / 128, BT / 128), 256, 0, stream>>>(hprev, wshb, HS, BT, HID, HID, nullptr);
  gemm_bt<<<dim3(HID / 128, (BL + 127) / 128), 256, 0, stream>>>(Hbf, wahb, AH, BL, HID, HID, nullptr);
  gemm_bt<<<dim3(HID / 128, (BL + 127) / 128), 256, 0, stream>>>(Gbf, wagb, AG, BL, HID, HID, nullptr);

  // --- gate / q / switch ---
  k_qmean<<<BB, 256, 0, stream>>>(XW, qb);
  k_st<<<nblk((long)BT * HID), 256, 0, stream>>>(XW, HS, cells, stbf, BT * HID);
  k_switch<<<BL, 256, 0, stream>>>(AH, AG, qb, w_sw, H, G, Vbf, swout);

  // --- skinny GEMMs (N=49 padded to 64 stored / 128 tiled) ---
  gemm_bt<<<dim3(1, (BL + 127) / 128), 256, 0, stream>>>(Vbf, wvb, PV, BL, 64, HID, nullptr);
  gemm_bt<<<dim3(1, BT / 128), 256, 0, stream>>>(hidbf, wgb, PG, BT, 64, HID, nullptr);
  gemm_bt<<<dim3(1, BT / 128), 256, 0, stream>>>(stbf, wsb, SS, BT, 64, HID, nullptr);

  // --- attention epilogue ---
  k_attn<<<BB * (TT / 4), 256, 0, stream>>>(PV, PG, SS, wh, stbf, Vbf, hiddens,
                                            alpha, beta, chh);

  // --- scores GEMM (+bias) ---
  gemm_bt<<<dim3(NPAD_MLP / 128, BT / 128), 256, 0, stream>>>(chh, wmlpb, scores, BT, VOC, HID, b_mlp);
}

// Round 2
// 468.672 us; speedup vs baseline: 1.0852x; 1.0852x over previous
//
#include <hip/hip_runtime.h>

#define BB 64
#define TT 60
#define LL 49
#define HID 768
#define E2 1536
#define VOC 10000
#define BT (BB*TT)      // 3840
#define BL (BB*LL)      // 3136
#define NPAD_MLP 10112  // 79*128
#define NPAD_S 128

typedef __bf16 bf16x8 __attribute__((ext_vector_type(8)));
typedef float f32x4 __attribute__((ext_vector_type(4)));

__device__ __forceinline__ unsigned short f2bf(float f) {
  union { float f; unsigned int u; } v; v.f = f;
  unsigned int u = v.u;
  return (unsigned short)((u + 0x7fffu + ((u >> 16) & 1u)) >> 16);  // RNE
}
__device__ __forceinline__ float bf2f(unsigned short h) {
  union { unsigned int u; float f; } v; v.u = ((unsigned int)h) << 16;
  return v.f;
}
__device__ __forceinline__ float fast_tanh(float x) {
  float e = __expf(2.f * x);
  return 1.f - 2.f / (e + 1.f);
}
__device__ __forceinline__ float fast_sigmoid(float x) {
  return 1.f / (1.f + __expf(-x));
}

// ---------------- fused convert: all fp32->bf16 staging in ONE kernel ----------------
#define NSEG 14
#define CHUNK4 2048   // vec4 elements per block
struct SegT {
  const float* src;
  unsigned short* dst;
  int n4;      // total vec4 elements in dst
  int nrows;   // pad mode: valid rows (row length fixed = 192 vec4)
  int mode;    // 0 plain, 1 pad-rows, 2 timestep-shift
  int blk0;    // first block id of this segment
};
struct SegTable { SegT s[NSEG]; };

__global__ __launch_bounds__(256) void k_convall(SegTable tab) {
  int b = blockIdx.x;
  int si = 0;
#pragma unroll
  for (int i = 1; i < NSEG; ++i) si += (b >= tab.s[i].blk0);
  SegT sg = tab.s[si];
  int lb = b - sg.blk0;
  int end = (lb + 1) * CHUNK4; end = end < sg.n4 ? end : sg.n4;
  for (int i = lb * CHUNK4 + threadIdx.x; i < end; i += 256) {
    ushort4 o; o.x = o.y = o.z = o.w = 0;
    if (sg.mode == 0) {
      float4 v = ((const float4*)sg.src)[i];
      o.x = f2bf(v.x); o.y = f2bf(v.y); o.z = f2bf(v.z); o.w = f2bf(v.w);
    } else if (sg.mode == 1) {          // zero-pad rows beyond nrows (row = 192 vec4)
      int row = i / 192;
      if (row < sg.nrows) {
        float4 v = ((const float4*)sg.src)[i];
        o.x = f2bf(v.x); o.y = f2bf(v.y); o.z = f2bf(v.z); o.w = f2bf(v.w);
      }
    } else {                            // hiddens_t_1 shift: t==0 -> 0 else row-1
      int bt = i / 192;
      if (bt % TT != 0) {
        float4 v = ((const float4*)sg.src)[i - 192];
        o.x = f2bf(v.x); o.y = f2bf(v.y); o.z = f2bf(v.z); o.w = f2bf(v.w);
      }
    }
    ((ushort4*)sg.dst)[i] = o;
  }
}

// ---------------- generic bf16 GEMM: C(MxNout) = A(MxK) * B(NxK)^T ----------------
// m97 structure + linear grid with bijective XCD chunk swizzle (m204) and
// COLUMN-MAJOR decode: consecutive work ids walk M with n0 fixed, so the ~32
// concurrent blocks per XCD share one B-tile (L2-resident); A stays L3-resident.
__global__ __launch_bounds__(256) void gemm_bt(
    const unsigned short* __restrict__ A,
    const unsigned short* __restrict__ Bw,
    float* __restrict__ C,
    int M, int Nout, int K,
    const float* __restrict__ bias,
    int nMblk)
{
  __shared__ __attribute__((aligned(16))) unsigned short As[128*32];
  __shared__ __attribute__((aligned(16))) unsigned short Bs[128*32];
  const int tid  = threadIdx.x;
  const int lane = tid & 63;
  const int wave = tid >> 6;

  // bijective XCD swizzle (m204): id -> contiguous chunk per XCD
  const int nwg = gridDim.x;
  const int id  = blockIdx.x;
  const int q = nwg >> 3, r = nwg & 7;
  const int xcd = id & 7, lo = id >> 3;
  const int wgid = (xcd < r ? xcd * (q + 1) : r * (q + 1) + (xcd - r) * q) + lo;
  const int mb = wgid % nMblk;
  const int nb = wgid / nMblk;
  const int m0 = mb * 128;
  const int n0 = nb * 128;
  const int wm = (wave >> 1) * 64;
  const int wn = (wave & 1) * 64;

  f32x4 acc[4][4];
#pragma unroll
  for (int i = 0; i < 4; ++i)
#pragma unroll
    for (int j = 0; j < 4; ++j) acc[i][j] = f32x4{0.f, 0.f, 0.f, 0.f};

  const int lrow = lane & 15;
  const int kb   = (lane >> 4) * 8;

  for (int k0 = 0; k0 < K; k0 += 32) {
    __syncthreads();
#pragma unroll
    for (int p = 0; p < 2; ++p) {
      int slot = p * 256 + wave * 64 + lane;
      int row = slot >> 2, c8 = slot & 3;
      int ar = m0 + row; ar = ar < M ? ar : (M - 1);
      const unsigned short* asrc = A + (size_t)ar * K + k0 + c8 * 8;
      __builtin_amdgcn_global_load_lds(
          (const __attribute__((address_space(1))) void*)asrc,
          (__attribute__((address_space(3))) void*)&As[(p * 256 + wave * 64) * 8],
          16, 0, 0);
      const unsigned short* bsrc = Bw + (size_t)(n0 + row) * K + k0 + c8 * 8;
      __builtin_amdgcn_global_load_lds(
          (const __attribute__((address_space(1))) void*)bsrc,
          (__attribute__((address_space(3))) void*)&Bs[(p * 256 + wave * 64) * 8],
          16, 0, 0);
    }
    __syncthreads();

    bf16x8 av[4], bv[4];
#pragma unroll
    for (int i = 0; i < 4; ++i)
      av[i] = *(const bf16x8*)&As[(wm + i * 16 + lrow) * 32 + kb];
#pragma unroll
    for (int j = 0; j < 4; ++j)
      bv[j] = *(const bf16x8*)&Bs[(wn + j * 16 + lrow) * 32 + kb];
#pragma unroll
    for (int i = 0; i < 4; ++i)
#pragma unroll
      for (int j = 0; j < 4; ++j)
        acc[i][j] = __builtin_amdgcn_mfma_f32_16x16x32_bf16(av[i], bv[j], acc[i][j], 0, 0, 0);
  }

  const int cr = (lane >> 4) * 4;
  const int cc = lane & 15;
#pragma unroll
  for (int i = 0; i < 4; ++i) {
    int row0 = m0 + wm + i * 16 + cr;
#pragma unroll
    for (int j = 0; j < 4; ++j) {
      int col = n0 + wn + j * 16 + cc;
      if (col < Nout) {
        float badd = bias ? bias[col] : 0.f;
#pragma unroll
        for (int r2 = 0; r2 < 4; ++r2) {
          int row = row0 + r2;
          if (row < M) C[(size_t)row * Nout + col] = acc[i][j][r2] + badd;
        }
      }
    }
  }
}

// ---------------- E1: q[b,h] = mean_t xa[b,t,h] ----------------
__global__ void k_qmean(const float* __restrict__ XW, float* __restrict__ q) {
  int b = blockIdx.x;
  for (int h = threadIdx.x; h < HID; h += blockDim.x) {
    float s = 0.f;
    for (int t = 0; t < TT; ++t) s += XW[(size_t)(b * TT + t) * E2 + HID + h];
    q[b * HID + h] = s * (1.f / 60.f);
  }
}

// ---------------- E2: s_t = sigmoid(xs + h_prev@W_sh^T) * tanh(cells) -> bf16 ----------------
__global__ void k_st(const float* __restrict__ XW, const float* __restrict__ HS,
                     const float* __restrict__ cells, unsigned short* __restrict__ stbf, int n) {
  int i = blockIdx.x * blockDim.x + threadIdx.x;
  int stride = gridDim.x * blockDim.x;
  for (; i < n; i += stride) {
    int bt = i / HID, h = i - bt * HID;
    float pre = XW[(size_t)bt * E2 + h] + HS[i];
    float v = fast_sigmoid(pre) * fast_tanh(cells[i]);
    stbf[i] = f2bf(v);
  }
}

// ---------------- E3: switch softmax + V = sw0*H + sw1*G ----------------
__global__ __launch_bounds__(256) void k_switch(
    const float* __restrict__ AH, const float* __restrict__ AG,
    const float* __restrict__ q, const float* __restrict__ wsw,
    const float* __restrict__ H, const float* __restrict__ G,
    unsigned short* __restrict__ Vbf, float* __restrict__ sw_out)
{
  int bl = blockIdx.x;
  int b = bl / LL;
  int tid = threadIdx.x;
  float aH = 0.f, aG = 0.f;
  for (int h = tid; h < HID; h += 256) {
    float qv = q[b * HID + h], w = wsw[h];
    aH += fast_tanh(AH[(size_t)bl * HID + h] + qv) * w;
    aG += fast_tanh(AG[(size_t)bl * HID + h] + qv) * w;
  }
#pragma unroll
  for (int off = 32; off > 0; off >>= 1) {
    aH += __shfl_down(aH, off);
    aG += __shfl_down(aG, off);
  }
  __shared__ float redH[4], redG[4];
  int lane = tid & 63, wave = tid >> 6;
  if (lane == 0) { redH[wave] = aH; redG[wave] = aG; }
  __syncthreads();
  float sH = redH[0] + redH[1] + redH[2] + redH[3];
  float sG = redG[0] + redG[1] + redG[2] + redG[3];
  float m = fmaxf(sH, sG);
  float e0 = __expf(sH - m), e1 = __expf(sG - m);
  float inv = 1.f / (e0 + e1);
  float sw0 = e0 * inv, sw1 = e1 * inv;
  if (tid == 0) { sw_out[bl * 2] = sw0; sw_out[bl * 2 + 1] = sw1; }
  for (int h = tid; h < HID; h += 256) {
    float v = sw0 * H[(size_t)bl * HID + h] + sw1 * G[(size_t)bl * HID + h];
    Vbf[(size_t)bl * HID + h] = f2bf(v);
  }
}

// ---------------- E4: z_t/z_s -> alpha/beta -> c_hat+hiddens (bf16) ----------------
__global__ __launch_bounds__(256) void k_attn(
    const float* __restrict__ PV, const float* __restrict__ PG,
    const float* __restrict__ SS, const float* __restrict__ wh,
    const unsigned short* __restrict__ stbf, const unsigned short* __restrict__ Vbf,
    const float* __restrict__ hiddens,
    float* __restrict__ alpha_out, float* __restrict__ beta_out,
    unsigned short* __restrict__ chh)
{
  const int TG = 4;
  int b  = blockIdx.x / (TT / TG);
  int t0 = (blockIdx.x % (TT / TG)) * TG;
  int tid = threadIdx.x;
  __shared__ float pg_s[TG][LL], wh_s[LL], zz[TG][LL + 1], alpha_s[TG][LL], beta_sh[TG];

  if (tid < LL) wh_s[tid] = wh[tid];
  if (tid < TG * LL) {
    int tt = tid / LL, k = tid - tt * LL;
    pg_s[tt][k] = PG[(size_t)(b * TT + t0 + tt) * 64 + k];
  }
  __syncthreads();

  if (tid < TG * (LL + 1)) {
    int tt = tid / (LL + 1), l = tid - tt * (LL + 1);
    const float* src = (l < LL) ? &PV[((size_t)b * LL + l) * 64]
                                : &SS[(size_t)(b * TT + t0 + tt) * 64];
    float acc = 0.f;
    for (int k = 0; k < LL; ++k) acc += fast_tanh(src[k] + pg_s[tt][k]) * wh_s[k];
    zz[tt][l] = acc;
  }
  __syncthreads();

  if (tid < TG) {
    int tt = tid, bt = b * TT + t0 + tt;
    float mx = -1e30f;
    for (int l = 0; l < LL; ++l) mx = fmaxf(mx, zz[tt][l]);
    float sum = 0.f;
    for (int l = 0; l < LL; ++l) { float e = __expf(zz[tt][l] - mx); alpha_s[tt][l] = e; sum += e; }
    float inv = 1.f / sum;
    for (int l = 0; l < LL; ++l) {
      alpha_s[tt][l] *= inv;
      alpha_out[(size_t)bt * LL + l] = alpha_s[tt][l];
    }
    float mx2 = fmaxf(mx, zz[tt][LL]);
    float s2 = 0.f;
    for (int l = 0; l <= LL; ++l) s2 += __expf(zz[tt][l] - mx2);
    float bet = __expf(zz[tt][LL] - mx2) / s2;
    beta_sh[tt] = bet;
    beta_out[bt] = bet;
  }
  __syncthreads();

  for (int h = tid; h < HID; h += 256) {
    float ct[TG] = {0.f, 0.f, 0.f, 0.f};
    for (int l = 0; l < LL; ++l) {
      float v = bf2f(Vbf[((size_t)b * LL + l) * HID + h]);
#pragma unroll
      for (int tt = 0; tt < TG; ++tt) ct[tt] += alpha_s[tt][l] * v;
    }
#pragma unroll
    for (int tt = 0; tt < TG; ++tt) {
      int bt = b * TT + t0 + tt;
      float bet = beta_sh[tt];
      float s = bf2f(stbf[(size_t)bt * HID + h]);
      float chat = bet * s + (1.f - bet) * ct[tt];
      chh[(size_t)bt * HID + h] = f2bf(chat + hiddens[(size_t)bt * HID + h]);
    }
  }
}

// ---------------- launcher ----------------
static inline int nblk(long n) {
  long g = (n + 255) / 256;
  if (g > 8192) g = 8192;
  return (int)g;
}

extern "C" void kernel_launch(void* const* d_in, const int* in_sizes, int n_in,
                              void* d_out, int out_size, void* d_ws, size_t ws_size,
                              hipStream_t stream)
{
  const float* x       = (const float*)d_in[0];
  const float* hiddens = (const float*)d_in[1];
  const float* cells   = (const float*)d_in[2];
  const float* G       = (const float*)d_in[3];
  const float* H       = (const float*)d_in[4];
  const float* W_sx    = (const float*)d_in[5];
  const float* W_sh    = (const float*)d_in[6];
  const float* W_ax    = (const float*)d_in[7];
  const float* W_ah    = (const float*)d_in[8];
  const float* W_ag    = (const float*)d_in[9];
  const float* w_sw    = (const float*)d_in[10];
  const float* Wv      = (const float*)d_in[11];
  const float* Wg      = (const float*)d_in[12];
  const float* Ws      = (const float*)d_in[13];
  const float* wh      = (const float*)d_in[14];
  const float* W_mlp   = (const float*)d_in[15];
  const float* b_mlp   = (const float*)d_in[16];

  float* scores = (float*)d_out;
  float* alpha  = scores + (size_t)BT * VOC;
  float* beta   = alpha + (size_t)BT * LL;
  float* swout  = beta + BT;

  char* wsp = (char*)d_ws;
  size_t off = 0;
  auto alloc = [&](size_t bytes) -> char* {
    char* p = wsp + off;
    off += (bytes + 255) & ~(size_t)255;
    return p;
  };

  unsigned short* xbf    = (unsigned short*)alloc((size_t)BT * E2 * 2);
  unsigned short* wsa    = (unsigned short*)alloc((size_t)E2 * E2 * 2);
  unsigned short* hprev  = (unsigned short*)alloc((size_t)BT * HID * 2);
  unsigned short* wshb   = (unsigned short*)alloc((size_t)HID * HID * 2);
  unsigned short* wahb   = (unsigned short*)alloc((size_t)HID * HID * 2);
  unsigned short* wagb   = (unsigned short*)alloc((size_t)HID * HID * 2);
  unsigned short* Hbf    = (unsigned short*)alloc((size_t)BL * HID * 2);
  unsigned short* Gbf    = (unsigned short*)alloc((size_t)BL * HID * 2);
  unsigned short* hidbf  = (unsigned short*)alloc((size_t)BT * HID * 2);
  unsigned short* wvb    = (unsigned short*)alloc((size_t)NPAD_S * HID * 2);
  unsigned short* wgb    = (unsigned short*)alloc((size_t)NPAD_S * HID * 2);
  unsigned short* wsb    = (unsigned short*)alloc((size_t)NPAD_S * HID * 2);
  unsigned short* wmlpb  = (unsigned short*)alloc((size_t)NPAD_MLP * HID * 2);
  unsigned short* Vbf    = (unsigned short*)alloc((size_t)BL * HID * 2);
  unsigned short* stbf   = (unsigned short*)alloc((size_t)BT * HID * 2);
  unsigned short* chh    = (unsigned short*)alloc((size_t)BT * HID * 2);
  float* XW = (float*)alloc((size_t)BT * E2 * 4);
  float* HS = (float*)alloc((size_t)BT * HID * 4);
  float* AH = (float*)alloc((size_t)BL * HID * 4);
  float* AG = (float*)alloc((size_t)BL * HID * 4);
  float* qb = (float*)alloc((size_t)BB * HID * 4);
  float* PV = (float*)alloc((size_t)BL * 64 * 4);
  float* PG = (float*)alloc((size_t)BT * 64 * 4);
  float* SS = (float*)alloc((size_t)BT * 64 * 4);
  (void)ws_size; (void)in_sizes; (void)n_in; (void)out_size;

  // --- one fused convert dispatch ---
  SegTable tab;
  int blk = 0, si = 0;
  auto seg = [&](const float* s, unsigned short* d, int n4, int nrows, int mode) {
    tab.s[si].src = s; tab.s[si].dst = d; tab.s[si].n4 = n4;
    tab.s[si].nrows = nrows; tab.s[si].mode = mode; tab.s[si].blk0 = blk;
    blk += (n4 + CHUNK4 - 1) / CHUNK4; ++si;
  };
  seg(W_sx, wsa,                        HID * E2 / 4, 0, 0);
  seg(W_ax, wsa + (size_t)HID * E2,     HID * E2 / 4, 0, 0);
  seg(x, xbf,                           BT * E2 / 4, 0, 0);
  seg(hiddens, hprev,                   BT * HID / 4, 0, 2);
  seg(W_sh, wshb,                       HID * HID / 4, 0, 0);
  seg(W_ah, wahb,                       HID * HID / 4, 0, 0);
  seg(W_ag, wagb,                       HID * HID / 4, 0, 0);
  seg(H, Hbf,                           BL * HID / 4, 0, 0);
  seg(G, Gbf,                           BL * HID / 4, 0, 0);
  seg(hiddens, hidbf,                   BT * HID / 4, 0, 0);
  seg(Wv, wvb,                          NPAD_S * HID / 4, LL, 1);
  seg(Wg, wgb,                          NPAD_S * HID / 4, LL, 1);
  seg(Ws, wsb,                          NPAD_S * HID / 4, LL, 1);
  seg(W_mlp, wmlpb,                     NPAD_MLP * HID / 4, VOC, 1);
  k_convall<<<blk, 256, 0, stream>>>(tab);

  // --- big GEMMs (linear grid, XCD-chunked, column-major decode) ---
  gemm_bt<<<30 * 12, 256, 0, stream>>>(xbf, wsa, XW, BT, E2, E2, nullptr, 30);
  gemm_bt<<<30 * 6,  256, 0, stream>>>(hprev, wshb, HS, BT, HID, HID, nullptr, 30);
  gemm_bt<<<25 * 6,  256, 0, stream>>>(Hbf, wahb, AH, BL, HID, HID, nullptr, 25);
  gemm_bt<<<25 * 6,  256, 0, stream>>>(Gbf, wagb, AG, BL, HID, HID, nullptr, 25);

  // --- gate / q / switch ---
  k_qmean<<<BB, 256, 0, stream>>>(XW, qb);
  k_st<<<nblk((long)BT * HID), 256, 0, stream>>>(XW, HS, cells, stbf, BT * HID);
  k_switch<<<BL, 256, 0, stream>>>(AH, AG, qb, w_sw, H, G, Vbf, swout);

  // --- skinny GEMMs ---
  gemm_bt<<<25, 256, 0, stream>>>(Vbf, wvb, PV, BL, 64, HID, nullptr, 25);
  gemm_bt<<<30, 256, 0, stream>>>(hidbf, wgb, PG, BT, 64, HID, nullptr, 30);
  gemm_bt<<<30, 256, 0, stream>>>(stbf, wsb, SS, BT, 64, HID, nullptr, 30);

  // --- attention epilogue ---
  k_attn<<<BB * (TT / 4), 256, 0, stream>>>(PV, PG, SS, wh, stbf, Vbf, hiddens,
                                            alpha, beta, chh);

  // --- scores GEMM (+bias) ---
  gemm_bt<<<30 * 79, 256, 0, stream>>>(chh, wmlpb, scores, BT, VOC, HID, b_mlp, 30);
}

// Round 3
// 425.932 us; speedup vs baseline: 1.1941x; 1.1003x over previous
//
#include <hip/hip_runtime.h>

#define BB 64
#define TT 60
#define LL 49
#define HID 768
#define E2 1536
#define VOC 10000
#define BT (BB*TT)      // 3840
#define BL (BB*LL)      // 3136
#define NPAD_MLP 10240  // 40*256 (256-tile grid coverage, zero-padded)
#define NPAD_S 128

typedef __bf16 bf16x8 __attribute__((ext_vector_type(8)));
typedef float f32x4 __attribute__((ext_vector_type(4)));

__device__ __forceinline__ unsigned short f2bf(float f) {
  union { float f; unsigned int u; } v; v.f = f;
  unsigned int u = v.u;
  return (unsigned short)((u + 0x7fffu + ((u >> 16) & 1u)) >> 16);  // RNE
}
__device__ __forceinline__ float bf2f(unsigned short h) {
  union { unsigned int u; float f; } v; v.u = ((unsigned int)h) << 16;
  return v.f;
}
__device__ __forceinline__ float fast_tanh(float x) {
  float e = __expf(2.f * x);
  return 1.f - 2.f / (e + 1.f);
}
__device__ __forceinline__ float fast_sigmoid(float x) {
  return 1.f / (1.f + __expf(-x));
}

// ---------------- fused convert: all fp32->bf16 staging in ONE kernel ----------------
#define NSEG 14
#define CHUNK4 2048
struct SegT {
  const float* src;
  unsigned short* dst;
  int n4;
  int nrows;
  int mode;    // 0 plain, 1 pad-rows, 2 timestep-shift
  int blk0;
};
struct SegTable { SegT s[NSEG]; };

__global__ __launch_bounds__(256) void k_convall(SegTable tab) {
  int b = blockIdx.x;
  int si = 0;
#pragma unroll
  for (int i = 1; i < NSEG; ++i) si += (b >= tab.s[i].blk0);
  SegT sg = tab.s[si];
  int lb = b - sg.blk0;
  int end = (lb + 1) * CHUNK4; end = end < sg.n4 ? end : sg.n4;
  for (int i = lb * CHUNK4 + threadIdx.x; i < end; i += 256) {
    ushort4 o; o.x = o.y = o.z = o.w = 0;
    if (sg.mode == 0) {
      float4 v = ((const float4*)sg.src)[i];
      o.x = f2bf(v.x); o.y = f2bf(v.y); o.z = f2bf(v.z); o.w = f2bf(v.w);
    } else if (sg.mode == 1) {
      int row = i / 192;
      if (row < sg.nrows) {
        float4 v = ((const float4*)sg.src)[i];
        o.x = f2bf(v.x); o.y = f2bf(v.y); o.z = f2bf(v.z); o.w = f2bf(v.w);
      }
    } else {
      int bt = i / 192;
      if (bt % TT != 0) {
        float4 v = ((const float4*)sg.src)[i - 192];
        o.x = f2bf(v.x); o.y = f2bf(v.y); o.z = f2bf(v.z); o.w = f2bf(v.w);
      }
    }
    ((ushort4*)sg.dst)[i] = o;
  }
}

// ---------------- 128^2 2-phase GEMM (kept for mid/skinny GEMMs) ----------------
__global__ __launch_bounds__(256) void gemm_bt(
    const unsigned short* __restrict__ A,
    const unsigned short* __restrict__ Bw,
    float* __restrict__ C,
    int M, int Nout, int K,
    const float* __restrict__ bias,
    int nMblk)
{
  __shared__ __attribute__((aligned(16))) unsigned short As[128*32];
  __shared__ __attribute__((aligned(16))) unsigned short Bs[128*32];
  const int tid  = threadIdx.x;
  const int lane = tid & 63;
  const int wave = tid >> 6;

  const int nwg = gridDim.x;
  const int id  = blockIdx.x;
  const int q = nwg >> 3, r = nwg & 7;
  const int xcd = id & 7, lo = id >> 3;
  const int wgid = (xcd < r ? xcd * (q + 1) : r * (q + 1) + (xcd - r) * q) + lo;
  const int mb = wgid % nMblk;
  const int nb = wgid / nMblk;
  const int m0 = mb * 128;
  const int n0 = nb * 128;
  const int wm = (wave >> 1) * 64;
  const int wn = (wave & 1) * 64;

  f32x4 acc[4][4];
#pragma unroll
  for (int i = 0; i < 4; ++i)
#pragma unroll
    for (int j = 0; j < 4; ++j) acc[i][j] = f32x4{0.f, 0.f, 0.f, 0.f};

  const int lrow = lane & 15;
  const int kb   = (lane >> 4) * 8;

  for (int k0 = 0; k0 < K; k0 += 32) {
    __syncthreads();
#pragma unroll
    for (int p = 0; p < 2; ++p) {
      int slot = p * 256 + wave * 64 + lane;
      int row = slot >> 2, c8 = slot & 3;
      int ar = m0 + row; ar = ar < M ? ar : (M - 1);
      const unsigned short* asrc = A + (size_t)ar * K + k0 + c8 * 8;
      __builtin_amdgcn_global_load_lds(
          (const __attribute__((address_space(1))) void*)asrc,
          (__attribute__((address_space(3))) void*)&As[(p * 256 + wave * 64) * 8],
          16, 0, 0);
      const unsigned short* bsrc = Bw + (size_t)(n0 + row) * K + k0 + c8 * 8;
      __builtin_amdgcn_global_load_lds(
          (const __attribute__((address_space(1))) void*)bsrc,
          (__attribute__((address_space(3))) void*)&Bs[(p * 256 + wave * 64) * 8],
          16, 0, 0);
    }
    __syncthreads();

    bf16x8 av[4], bv[4];
#pragma unroll
    for (int i = 0; i < 4; ++i)
      av[i] = *(const bf16x8*)&As[(wm + i * 16 + lrow) * 32 + kb];
#pragma unroll
    for (int j = 0; j < 4; ++j)
      bv[j] = *(const bf16x8*)&Bs[(wn + j * 16 + lrow) * 32 + kb];
#pragma unroll
    for (int i = 0; i < 4; ++i)
#pragma unroll
      for (int j = 0; j < 4; ++j)
        acc[i][j] = __builtin_amdgcn_mfma_f32_16x16x32_bf16(av[i], bv[j], acc[i][j], 0, 0, 0);
  }

  const int cr = (lane >> 4) * 4;
  const int cc = lane & 15;
#pragma unroll
  for (int i = 0; i < 4; ++i) {
    int row0 = m0 + wm + i * 16 + cr;
#pragma unroll
    for (int j = 0; j < 4; ++j) {
      int col = n0 + wn + j * 16 + cc;
      if (col < Nout) {
        float badd = bias ? bias[col] : 0.f;
#pragma unroll
        for (int r2 = 0; r2 < 4; ++r2) {
          int row = row0 + r2;
          if (row < M) C[(size_t)row * Nout + col] = acc[i][j][r2] + badd;
        }
      }
    }
  }
}

// ---------------- 256^2 8-wave, 4-phase/K-tile pipelined GEMM (scores) ----------------
// Requires: M % 256 == 0; B zero-padded to >= gridN*256 rows; K % 64 == 0, K/64 >= 3.
// LDS: [buf2][op2][kk2] panels of 256x32 bf16 (16 KB each) = 128 KB.
// Swizzle: 16B-slot s' = s ^ ((r>>1)&3), applied to stage SOURCE addr and ds_read addr.
#define BARR() do { asm volatile("" ::: "memory"); __builtin_amdgcn_s_barrier(); \
                    asm volatile("" ::: "memory"); } while (0)
#define VM8() asm volatile("s_waitcnt vmcnt(8)" ::: "memory")
#define VM4() asm volatile("s_waitcnt vmcnt(4)" ::: "memory")
#define VM0() asm volatile("s_waitcnt vmcnt(0)" ::: "memory")

#define STAGE_UNIT(b, op, kk, kt) do {                                          \
  const unsigned short* gbase_ = (op) ? (Bw + (size_t)n0 * K) : (A + (size_t)m0 * K); \
  int k0_ = (kt) * 64 + (kk) * 32;                                              \
  _Pragma("unroll")                                                             \
  for (int l_ = 0; l_ < 2; ++l_) {                                              \
    int rr_ = l_ * 128 + sr0;                                                   \
    int ss_ = ssp ^ ((rr_ >> 1) & 3);                                           \
    const unsigned short* src_ = gbase_ + (size_t)rr_ * K + k0_ + ss_ * 8;      \
    char* dst_ = smem + (((b) * 4 + (op) * 2 + (kk)) * 16384) + l_ * 8192 + w * 1024; \
    __builtin_amdgcn_global_load_lds(                                           \
        (const __attribute__((address_space(1))) void*)src_,                    \
        (__attribute__((address_space(3))) void*)dst_, 16, 0, 0);               \
  }                                                                             \
} while (0)

#define PHASE(c, KK, JH, STAGE_STMT, VM_STMT) do {                              \
  if ((JH) == 0) {                                                              \
    _Pragma("unroll")                                                           \
    for (int i_ = 0; i_ < 8; ++i_) {                                            \
      int rr_ = wm + i_ * 16 + lrow;                                            \
      int sp_ = cg ^ ((rr_ >> 1) & 3);                                          \
      afr[i_] = *(const bf16x8*)(smem + ((c) * 4 + 0 * 2 + (KK)) * 16384 + rr_ * 64 + sp_ * 16); \
    }                                                                           \
  }                                                                             \
  {                                                                             \
    int rb0_ = wn + ((JH) * 2) * 16 + lrow;                                     \
    int sb0_ = cg ^ ((rb0_ >> 1) & 3);                                          \
    bfr0 = *(const bf16x8*)(smem + ((c) * 4 + 2 + (KK)) * 16384 + rb0_ * 64 + sb0_ * 16); \
    int rb1_ = wn + ((JH) * 2 + 1) * 16 + lrow;                                 \
    int sb1_ = cg ^ ((rb1_ >> 1) & 3);                                          \
    bfr1 = *(const bf16x8*)(smem + ((c) * 4 + 2 + (KK)) * 16384 + rb1_ * 64 + sb1_ * 16); \
  }                                                                             \
  STAGE_STMT;                                                                   \
  BARR();                                                                       \
  asm volatile("s_waitcnt lgkmcnt(0)" ::: "memory");                            \
  __builtin_amdgcn_sched_barrier(0);                                            \
  __builtin_amdgcn_s_setprio(1);                                                \
  _Pragma("unroll")                                                             \
  for (int i_ = 0; i_ < 8; ++i_) {                                              \
    acc[i_][(JH) * 2]     = __builtin_amdgcn_mfma_f32_16x16x32_bf16(afr[i_], bfr0, acc[i_][(JH) * 2], 0, 0, 0);     \
    acc[i_][(JH) * 2 + 1] = __builtin_amdgcn_mfma_f32_16x16x32_bf16(afr[i_], bfr1, acc[i_][(JH) * 2 + 1], 0, 0, 0); \
  }                                                                             \
  __builtin_amdgcn_s_setprio(0);                                                \
  VM_STMT;                                                                      \
  BARR();                                                                       \
} while (0)

__global__ __launch_bounds__(512, 2) void gemm8p(
    const unsigned short* __restrict__ A,
    const unsigned short* __restrict__ Bw,
    float* __restrict__ C,
    int M, int Nout, int K,
    const float* __restrict__ bias,
    int nMblk)
{
  extern __shared__ char smem[];
  const int tid  = threadIdx.x;
  const int lane = tid & 63;
  const int w    = tid >> 6;       // 0..7
  const int lrow = lane & 15;
  const int cg   = lane >> 4;      // 0..3
  const int sr0  = w * 16 + (lane >> 2);  // stage row for l=0
  const int ssp  = lane & 3;              // stage 16B slot (physical)

  const int nwg = gridDim.x;
  const int id  = blockIdx.x;
  const int q = nwg >> 3, r = nwg & 7;
  const int xcd = id & 7, lo = id >> 3;
  const int wgid = (xcd < r ? xcd * (q + 1) : r * (q + 1) + (xcd - r) * q) + lo;
  const int mb = wgid % nMblk;
  const int nb = wgid / nMblk;
  const int m0 = mb * 256;
  const int n0 = nb * 256;
  const int wm = (w >> 2) * 128;   // 0 or 128
  const int wn = (w & 3) * 64;     // 0,64,128,192

  f32x4 acc[8][4];
#pragma unroll
  for (int i = 0; i < 8; ++i)
#pragma unroll
    for (int j = 0; j < 4; ++j) acc[i][j] = f32x4{0.f, 0.f, 0.f, 0.f};
  bf16x8 afr[8];
  bf16x8 bfr0, bfr1;

  const int NT = K >> 6;  // K/64, >= 3

  // prologue: stage kt0 fully + kt1 kk0 (12 loads); need first 4 -> vmcnt(8)
  STAGE_UNIT(0, 0, 0, 0);
  STAGE_UNIT(0, 1, 0, 0);
  STAGE_UNIT(0, 0, 1, 0);
  STAGE_UNIT(0, 1, 1, 0);
  STAGE_UNIT(1, 0, 0, 1);
  STAGE_UNIT(1, 1, 0, 1);
  VM8();
  BARR();

  // main loop: kt in [0, NT-3]
  for (int kt = 0; kt < NT - 2; ++kt) {
    const int c = kt & 1;
    PHASE(c, 0, 0, STAGE_UNIT(c ^ 1, 0, 1, kt + 1), ;);
    PHASE(c, 0, 1, STAGE_UNIT(c ^ 1, 1, 1, kt + 1), VM8(););
    PHASE(c, 1, 0, STAGE_UNIT(c,     0, 0, kt + 2), ;);
    PHASE(c, 1, 1, STAGE_UNIT(c,     1, 0, kt + 2), VM8(););
  }
  // kt = NT-2: no kk0 staging for kt+2 (doesn't exist)
  {
    const int kt = NT - 2;
    const int c = kt & 1;
    PHASE(c, 0, 0, STAGE_UNIT(c ^ 1, 0, 1, kt + 1), ;);
    PHASE(c, 0, 1, STAGE_UNIT(c ^ 1, 1, 1, kt + 1), VM8(););
    PHASE(c, 1, 0, ;, ;);
    PHASE(c, 1, 1, ;, VM4(););
  }
  // kt = NT-1: no staging; drain before kk1 reads
  {
    const int c = (NT - 1) & 1;
    PHASE(c, 0, 0, ;, ;);
    PHASE(c, 0, 1, ;, VM0(););
    PHASE(c, 1, 0, ;, ;);
    PHASE(c, 1, 1, ;, ;);
  }

  // epilogue: C/D layout col=lane&15, row=(lane>>4)*4+reg
#pragma unroll
  for (int i = 0; i < 8; ++i) {
    int row = m0 + wm + i * 16 + (lane >> 4) * 4;
#pragma unroll
    for (int j = 0; j < 4; ++j) {
      int col = n0 + wn + j * 16 + (lane & 15);
      if (col < Nout) {
        float badd = bias ? bias[col] : 0.f;
#pragma unroll
        for (int r2 = 0; r2 < 4; ++r2)
          C[(size_t)(row + r2) * Nout + col] = acc[i][j][r2] + badd;
      }
    }
  }
}

// ---------------- E1: q[b,h] = mean_t xa[b,t,h] ----------------
__global__ __launch_bounds__(256) void k_qmean(const float* __restrict__ XW, float* __restrict__ q) {
  int b = blockIdx.x / 3;
  int h = (blockIdx.x % 3) * 256 + threadIdx.x;
  float s = 0.f;
  for (int t = 0; t < TT; ++t) s += XW[(size_t)(b * TT + t) * E2 + HID + h];
  q[b * HID + h] = s * (1.f / 60.f);
}

// ---------------- E2 ----------------
__global__ void k_st(const float* __restrict__ XW, const float* __restrict__ HS,
                     const float* __restrict__ cells, unsigned short* __restrict__ stbf, int n) {
  int i = blockIdx.x * blockDim.x + threadIdx.x;
  int stride = gridDim.x * blockDim.x;
  for (; i < n; i += stride) {
    int bt = i / HID, h = i - bt * HID;
    float pre = XW[(size_t)bt * E2 + h] + HS[i];
    float v = fast_sigmoid(pre) * fast_tanh(cells[i]);
    stbf[i] = f2bf(v);
  }
}

// ---------------- E3 ----------------
__global__ __launch_bounds__(256) void k_switch(
    const float* __restrict__ AH, const float* __restrict__ AG,
    const float* __restrict__ q, const float* __restrict__ wsw,
    const float* __restrict__ H, const float* __restrict__ G,
    unsigned short* __restrict__ Vbf, float* __restrict__ sw_out)
{
  int bl = blockIdx.x;
  int b = bl / LL;
  int tid = threadIdx.x;
  float aH = 0.f, aG = 0.f;
  for (int h = tid; h < HID; h += 256) {
    float qv = q[b * HID + h], w = wsw[h];
    aH += fast_tanh(AH[(size_t)bl * HID + h] + qv) * w;
    aG += fast_tanh(AG[(size_t)bl * HID + h] + qv) * w;
  }
#pragma unroll
  for (int off = 32; off > 0; off >>= 1) {
    aH += __shfl_down(aH, off);
    aG += __shfl_down(aG, off);
  }
  __shared__ float redH[4], redG[4];
  int lane = tid & 63, wave = tid >> 6;
  if (lane == 0) { redH[wave] = aH; redG[wave] = aG; }
  __syncthreads();
  float sH = redH[0] + redH[1] + redH[2] + redH[3];
  float sG = redG[0] + redG[1] + redG[2] + redG[3];
  float m = fmaxf(sH, sG);
  float e0 = __expf(sH - m), e1 = __expf(sG - m);
  float inv = 1.f / (e0 + e1);
  float sw0 = e0 * inv, sw1 = e1 * inv;
  if (tid == 0) { sw_out[bl * 2] = sw0; sw_out[bl * 2 + 1] = sw1; }
  for (int h = tid; h < HID; h += 256) {
    float v = sw0 * H[(size_t)bl * HID + h] + sw1 * G[(size_t)bl * HID + h];
    Vbf[(size_t)bl * HID + h] = f2bf(v);
  }
}

// ---------------- E4 ----------------
__global__ __launch_bounds__(256) void k_attn(
    const float* __restrict__ PV, const float* __restrict__ PG,
    const float* __restrict__ SS, const float* __restrict__ wh,
    const unsigned short* __restrict__ stbf, const unsigned short* __restrict__ Vbf,
    const float* __restrict__ hiddens,
    float* __restrict__ alpha_out, float* __restrict__ beta_out,
    unsigned short* __restrict__ chh)
{
  const int TG = 4;
  int b  = blockIdx.x / (TT / TG);
  int t0 = (blockIdx.x % (TT / TG)) * TG;
  int tid = threadIdx.x;
  __shared__ float pg_s[TG][LL], wh_s[LL], zz[TG][LL + 1], alpha_s[TG][LL], beta_sh[TG];

  if (tid < LL) wh_s[tid] = wh[tid];
  if (tid < TG * LL) {
    int tt = tid / LL, k = tid - tt * LL;
    pg_s[tt][k] = PG[(size_t)(b * TT + t0 + tt) * 64 + k];
  }
  __syncthreads();

  if (tid < TG * (LL + 1)) {
    int tt = tid / (LL + 1), l = tid - tt * (LL + 1);
    const float* src = (l < LL) ? &PV[((size_t)b * LL + l) * 64]
                                : &SS[(size_t)(b * TT + t0 + tt) * 64];
    float acc = 0.f;
    for (int k = 0; k < LL; ++k) acc += fast_tanh(src[k] + pg_s[tt][k]) * wh_s[k];
    zz[tt][l] = acc;
  }
  __syncthreads();

  if (tid < TG) {
    int tt = tid, bt = b * TT + t0 + tt;
    float mx = -1e30f;
    for (int l = 0; l < LL; ++l) mx = fmaxf(mx, zz[tt][l]);
    float sum = 0.f;
    for (int l = 0; l < LL; ++l) { float e = __expf(zz[tt][l] - mx); alpha_s[tt][l] = e; sum += e; }
    float inv = 1.f / sum;
    for (int l = 0; l < LL; ++l) {
      alpha_s[tt][l] *= inv;
      alpha_out[(size_t)bt * LL + l] = alpha_s[tt][l];
    }
    float mx2 = fmaxf(mx, zz[tt][LL]);
    float s2 = 0.f;
    for (int l = 0; l <= LL; ++l) s2 += __expf(zz[tt][l] - mx2);
    float bet = __expf(zz[tt][LL] - mx2) / s2;
    beta_sh[tt] = bet;
    beta_out[bt] = bet;
  }
  __syncthreads();

  for (int h = tid; h < HID; h += 256) {
    float ct[TG] = {0.f, 0.f, 0.f, 0.f};
    for (int l = 0; l < LL; ++l) {
      float v = bf2f(Vbf[((size_t)b * LL + l) * HID + h]);
#pragma unroll
      for (int tt = 0; tt < TG; ++tt) ct[tt] += alpha_s[tt][l] * v;
    }
#pragma unroll
    for (int tt = 0; tt < TG; ++tt) {
      int bt = b * TT + t0 + tt;
      float bet = beta_sh[tt];
      float s = bf2f(stbf[(size_t)bt * HID + h]);
      float chat = bet * s + (1.f - bet) * ct[tt];
      chh[(size_t)bt * HID + h] = f2bf(chat + hiddens[(size_t)bt * HID + h]);
    }
  }
}

// ---------------- launcher ----------------
static inline int nblk(long n) {
  long g = (n + 255) / 256;
  if (g > 8192) g = 8192;
  return (int)g;
}

extern "C" void kernel_launch(void* const* d_in, const int* in_sizes, int n_in,
                              void* d_out, int out_size, void* d_ws, size_t ws_size,
                              hipStream_t stream)
{
  const float* x       = (const float*)d_in[0];
  const float* hiddens = (const float*)d_in[1];
  const float* cells   = (const float*)d_in[2];
  const float* G       = (const float*)d_in[3];
  const float* H       = (const float*)d_in[4];
  const float* W_sx    = (const float*)d_in[5];
  const float* W_sh    = (const float*)d_in[6];
  const float* W_ax    = (const float*)d_in[7];
  const float* W_ah    = (const float*)d_in[8];
  const float* W_ag    = (const float*)d_in[9];
  const float* w_sw    = (const float*)d_in[10];
  const float* Wv      = (const float*)d_in[11];
  const float* Wg      = (const float*)d_in[12];
  const float* Ws      = (const float*)d_in[13];
  const float* wh      = (const float*)d_in[14];
  const float* W_mlp   = (const float*)d_in[15];
  const float* b_mlp   = (const float*)d_in[16];

  float* scores = (float*)d_out;
  float* alpha  = scores + (size_t)BT * VOC;
  float* beta   = alpha + (size_t)BT * LL;
  float* swout  = beta + BT;

  char* wsp = (char*)d_ws;
  size_t off = 0;
  auto alloc = [&](size_t bytes) -> char* {
    char* p = wsp + off;
    off += (bytes + 255) & ~(size_t)255;
    return p;
  };

  unsigned short* xbf    = (unsigned short*)alloc((size_t)BT * E2 * 2);
  unsigned short* wsa    = (unsigned short*)alloc((size_t)E2 * E2 * 2);
  unsigned short* hprev  = (unsigned short*)alloc((size_t)BT * HID * 2);
  unsigned short* wshb   = (unsigned short*)alloc((size_t)HID * HID * 2);
  unsigned short* wahb   = (unsigned short*)alloc((size_t)HID * HID * 2);
  unsigned short* wagb   = (unsigned short*)alloc((size_t)HID * HID * 2);
  unsigned short* Hbf    = (unsigned short*)alloc((size_t)BL * HID * 2);
  unsigned short* Gbf    = (unsigned short*)alloc((size_t)BL * HID * 2);
  unsigned short* hidbf  = (unsigned short*)alloc((size_t)BT * HID * 2);
  unsigned short* wvb    = (unsigned short*)alloc((size_t)NPAD_S * HID * 2);
  unsigned short* wgb    = (unsigned short*)alloc((size_t)NPAD_S * HID * 2);
  unsigned short* wsb    = (unsigned short*)alloc((size_t)NPAD_S * HID * 2);
  unsigned short* wmlpb  = (unsigned short*)alloc((size_t)NPAD_MLP * HID * 2);
  unsigned short* Vbf    = (unsigned short*)alloc((size_t)BL * HID * 2);
  unsigned short* stbf   = (unsigned short*)alloc((size_t)BT * HID * 2);
  unsigned short* chh    = (unsigned short*)alloc((size_t)BT * HID * 2);
  float* XW = (float*)alloc((size_t)BT * E2 * 4);
  float* HS = (float*)alloc((size_t)BT * HID * 4);
  float* AH = (float*)alloc((size_t)BL * HID * 4);
  float* AG = (float*)alloc((size_t)BL * HID * 4);
  float* qb = (float*)alloc((size_t)BB * HID * 4);
  float* PV = (float*)alloc((size_t)BL * 64 * 4);
  float* PG = (float*)alloc((size_t)BT * 64 * 4);
  float* SS = (float*)alloc((size_t)BT * 64 * 4);
  (void)ws_size; (void)in_sizes; (void)n_in; (void)out_size;

  // --- one fused convert dispatch ---
  SegTable tab;
  int blk = 0, si = 0;
  auto seg = [&](const float* s, unsigned short* d, int n4, int nrows, int mode) {
    tab.s[si].src = s; tab.s[si].dst = d; tab.s[si].n4 = n4;
    tab.s[si].nrows = nrows; tab.s[si].mode = mode; tab.s[si].blk0 = blk;
    blk += (n4 + CHUNK4 - 1) / CHUNK4; ++si;
  };
  seg(W_sx, wsa,                        HID * E2 / 4, 0, 0);
  seg(W_ax, wsa + (size_t)HID * E2,     HID * E2 / 4, 0, 0);
  seg(x, xbf,                           BT * E2 / 4, 0, 0);
  seg(hiddens, hprev,                   BT * HID / 4, 0, 2);
  seg(W_sh, wshb,                       HID * HID / 4, 0, 0);
  seg(W_ah, wahb,                       HID * HID / 4, 0, 0);
  seg(W_ag, wagb,                       HID * HID / 4, 0, 0);
  seg(H, Hbf,                           BL * HID / 4, 0, 0);
  seg(G, Gbf,                           BL * HID / 4, 0, 0);
  seg(hiddens, hidbf,                   BT * HID / 4, 0, 0);
  seg(Wv, wvb,                          NPAD_S * HID / 4, LL, 1);
  seg(Wg, wgb,                          NPAD_S * HID / 4, LL, 1);
  seg(Ws, wsb,                          NPAD_S * HID / 4, LL, 1);
  seg(W_mlp, wmlpb,                     NPAD_MLP * HID / 4, VOC, 1);
  k_convall<<<blk, 256, 0, stream>>>(tab);

  // --- big GEMMs (128^2 2-phase) ---
  gemm_bt<<<30 * 12, 256, 0, stream>>>(xbf, wsa, XW, BT, E2, E2, nullptr, 30);
  gemm_bt<<<30 * 6,  256, 0, stream>>>(hprev, wshb, HS, BT, HID, HID, nullptr, 30);
  gemm_bt<<<25 * 6,  256, 0, stream>>>(Hbf, wahb, AH, BL, HID, HID, nullptr, 25);
  gemm_bt<<<25 * 6,  256, 0, stream>>>(Gbf, wagb, AG, BL, HID, HID, nullptr, 25);

  // --- gate / q / switch ---
  k_qmean<<<BB * 3, 256, 0, stream>>>(XW, qb);
  k_st<<<nblk((long)BT * HID), 256, 0, stream>>>(XW, HS, cells, stbf, BT * HID);
  k_switch<<<BL, 256, 0, stream>>>(AH, AG, qb, w_sw, H, G, Vbf, swout);

  // --- skinny GEMMs ---
  gemm_bt<<<25, 256, 0, stream>>>(Vbf, wvb, PV, BL, 64, HID, nullptr, 25);
  gemm_bt<<<30, 256, 0, stream>>>(hidbf, wgb, PG, BT, 64, HID, nullptr, 30);
  gemm_bt<<<30, 256, 0, stream>>>(stbf, wsb, SS, BT, 64, HID, nullptr, 30);

  // --- attention epilogue ---
  k_attn<<<BB * (TT / 4), 256, 0, stream>>>(PV, PG, SS, wh, stbf, Vbf, hiddens,
                                            alpha, beta, chh);

  // --- scores GEMM: 256^2 8-phase pipelined (+bias), grid 15x40 = 600 ---
  gemm8p<<<15 * 40, 512, 131072, stream>>>(chh, wmlpb, scores, BT, VOC, HID, b_mlp, 15);
}

// Round 4
// 312.675 us; speedup vs baseline: 1.6266x; 1.3622x over previous
//
#include <hip/hip_runtime.h>

#define BB 64
#define TT 60
#define LL 49
#define HID 768
#define E2 1536
#define VOC 10000
#define BT (BB*TT)      // 3840
#define BL (BB*LL)      // 3136
#define NPAD_MLP 10240  // 40*256
#define NPAD_S 128

typedef __bf16 bf16x8 __attribute__((ext_vector_type(8)));
typedef float f32x4 __attribute__((ext_vector_type(4)));

__device__ __forceinline__ unsigned short f2bf(float f) {
  union { float f; unsigned int u; } v; v.f = f;
  unsigned int u = v.u;
  return (unsigned short)((u + 0x7fffu + ((u >> 16) & 1u)) >> 16);  // RNE
}
__device__ __forceinline__ float bf2f(unsigned short h) {
  union { unsigned int u; float f; } v; v.u = ((unsigned int)h) << 16;
  return v.f;
}
__device__ __forceinline__ float fast_tanh(float x) {
  float e = __expf(2.f * x);
  return 1.f - 2.f / (e + 1.f);
}
__device__ __forceinline__ float fast_sigmoid(float x) {
  return 1.f / (1.f + __expf(-x));
}

// ---------------- fused convert: all fp32->bf16 staging in ONE kernel ----------------
#define NSEG 14
#define CHUNK4 2048
struct SegT {
  const float* src;
  unsigned short* dst;
  int n4;
  int nrows;
  int mode;    // 0 plain, 1 pad-rows, 2 timestep-shift
  int blk0;
};
struct SegTable { SegT s[NSEG]; };

__global__ __launch_bounds__(256) void k_convall(SegTable tab) {
  int b = blockIdx.x;
  int si = 0;
#pragma unroll
  for (int i = 1; i < NSEG; ++i) si += (b >= tab.s[i].blk0);
  SegT sg = tab.s[si];
  int lb = b - sg.blk0;
  int end = (lb + 1) * CHUNK4; end = end < sg.n4 ? end : sg.n4;
  for (int i = lb * CHUNK4 + threadIdx.x; i < end; i += 256) {
    ushort4 o; o.x = o.y = o.z = o.w = 0;
    if (sg.mode == 0) {
      float4 v = ((const float4*)sg.src)[i];
      o.x = f2bf(v.x); o.y = f2bf(v.y); o.z = f2bf(v.z); o.w = f2bf(v.w);
    } else if (sg.mode == 1) {
      int row = i / 192;
      if (row < sg.nrows) {
        float4 v = ((const float4*)sg.src)[i];
        o.x = f2bf(v.x); o.y = f2bf(v.y); o.z = f2bf(v.z); o.w = f2bf(v.w);
      }
    } else {
      int bt = i / 192;
      if (bt % TT != 0) {
        float4 v = ((const float4*)sg.src)[i - 192];
        o.x = f2bf(v.x); o.y = f2bf(v.y); o.z = f2bf(v.z); o.w = f2bf(v.w);
      }
    }
    ((ushort4*)sg.dst)[i] = o;
  }
}

// ---------------- k_xmean: xm[b,c] = bf16(mean_t x[b,t,c]) ----------------
__global__ __launch_bounds__(256) void k_xmean(const float* __restrict__ x,
                                               unsigned short* __restrict__ xm) {
  int b = blockIdx.x / 6;
  int c = (blockIdx.x % 6) * 256 + threadIdx.x;
  float s = 0.f;
  for (int t = 0; t < TT; ++t) s += x[((size_t)b * TT + t) * E2 + c];
  xm[(size_t)b * E2 + c] = f2bf(s * (1.f / 60.f));
}

// ---------------- segmented 128^2 2-phase GEMM (skinny N=64 GEMMs) ----------------
struct SSeg {
  const unsigned short* A; const unsigned short* B; float* C;
  int M, Nout, K, nMblk, blk0;
};
#define NSSEG 3
struct SSegTable { SSeg s[NSSEG]; };

__global__ __launch_bounds__(256) void gemm_bt_seg(SSegTable tab)
{
  __shared__ __attribute__((aligned(16))) unsigned short As[128*32];
  __shared__ __attribute__((aligned(16))) unsigned short Bs[128*32];
  const int tid  = threadIdx.x;
  const int lane = tid & 63;
  const int wave = tid >> 6;

  const int nwg = gridDim.x;
  const int id  = blockIdx.x;
  const int q = nwg >> 3, r = nwg & 7;
  const int xcd = id & 7, lo = id >> 3;
  const int wgid = (xcd < r ? xcd * (q + 1) : r * (q + 1) + (xcd - r) * q) + lo;

  int si = 0;
#pragma unroll
  for (int i = 1; i < NSSEG; ++i) si += (wgid >= tab.s[i].blk0);
  const SSeg sg = tab.s[si];
  const int lwg = wgid - sg.blk0;
  const int mb = lwg % sg.nMblk;
  const int nb = lwg / sg.nMblk;
  const int M = sg.M, Nout = sg.Nout, K = sg.K;
  const unsigned short* __restrict__ A  = sg.A;
  const unsigned short* __restrict__ Bw = sg.B;
  float* __restrict__ C = sg.C;
  const int m0 = mb * 128;
  const int n0 = nb * 128;
  const int wm = (wave >> 1) * 64;
  const int wn = (wave & 1) * 64;

  f32x4 acc[4][4];
#pragma unroll
  for (int i = 0; i < 4; ++i)
#pragma unroll
    for (int j = 0; j < 4; ++j) acc[i][j] = f32x4{0.f, 0.f, 0.f, 0.f};

  const int lrow = lane & 15;
  const int kb   = (lane >> 4) * 8;

  for (int k0 = 0; k0 < K; k0 += 32) {
    __syncthreads();
#pragma unroll
    for (int p = 0; p < 2; ++p) {
      int slot = p * 256 + wave * 64 + lane;
      int row = slot >> 2, c8 = slot & 3;
      int ar = m0 + row; ar = ar < M ? ar : (M - 1);
      const unsigned short* asrc = A + (size_t)ar * K + k0 + c8 * 8;
      __builtin_amdgcn_global_load_lds(
          (const __attribute__((address_space(1))) void*)asrc,
          (__attribute__((address_space(3))) void*)&As[(p * 256 + wave * 64) * 8],
          16, 0, 0);
      const unsigned short* bsrc = Bw + (size_t)(n0 + row) * K + k0 + c8 * 8;
      __builtin_amdgcn_global_load_lds(
          (const __attribute__((address_space(1))) void*)bsrc,
          (__attribute__((address_space(3))) void*)&Bs[(p * 256 + wave * 64) * 8],
          16, 0, 0);
    }
    __syncthreads();

    bf16x8 av[4], bv[4];
#pragma unroll
    for (int i = 0; i < 4; ++i)
      av[i] = *(const bf16x8*)&As[(wm + i * 16 + lrow) * 32 + kb];
#pragma unroll
    for (int j = 0; j < 4; ++j)
      bv[j] = *(const bf16x8*)&Bs[(wn + j * 16 + lrow) * 32 + kb];
#pragma unroll
    for (int i = 0; i < 4; ++i)
#pragma unroll
      for (int j = 0; j < 4; ++j)
        acc[i][j] = __builtin_amdgcn_mfma_f32_16x16x32_bf16(av[i], bv[j], acc[i][j], 0, 0, 0);
  }

  const int cr = (lane >> 4) * 4;
  const int cc = lane & 15;
#pragma unroll
  for (int i = 0; i < 4; ++i) {
    int row0 = m0 + wm + i * 16 + cr;
#pragma unroll
    for (int j = 0; j < 4; ++j) {
      int col = n0 + wn + j * 16 + cc;
      if (col < Nout) {
#pragma unroll
        for (int r2 = 0; r2 < 4; ++r2) {
          int row = row0 + r2;
          if (row < M) C[(size_t)row * Nout + col] = acc[i][j][r2];
        }
      }
    }
  }
}

// ---------------- segmented 256^2 8-wave 4-phase/K-tile pipelined GEMM ----------------
// Per segment: M arbitrary (A-rows clamped, stores guarded); B zero-padded to
// nNblk*256 rows; K % 64 == 0, K/64 >= 3.
// LDS: [buf2][op2][kk2] panels of 256x32 bf16 (16 KB each) = 128 KB.
#define BARR() do { asm volatile("" ::: "memory"); __builtin_amdgcn_s_barrier(); \
                    asm volatile("" ::: "memory"); } while (0)
#define VM8() asm volatile("s_waitcnt vmcnt(8)" ::: "memory")
#define VM4() asm volatile("s_waitcnt vmcnt(4)" ::: "memory")
#define VM0() asm volatile("s_waitcnt vmcnt(0)" ::: "memory")

#define STAGE_UNIT(b, op, kk, kt) do {                                          \
  int k0_ = (kt) * 64 + (kk) * 32;                                              \
  _Pragma("unroll")                                                             \
  for (int l_ = 0; l_ < 2; ++l_) {                                              \
    int rr_ = l_ * 128 + sr0;                                                   \
    int ss_ = ssp ^ ((rr_ >> 1) & 3);                                           \
    int gr_ = (op) ? (n0 + rr_) : ((m0 + rr_) < M ? (m0 + rr_) : (M - 1));      \
    const unsigned short* src_ = ((op) ? Bw : Ap) + (size_t)gr_ * K + k0_ + ss_ * 8; \
    char* dst_ = smem + (((b) * 4 + (op) * 2 + (kk)) * 16384) + l_ * 8192 + w * 1024; \
    __builtin_amdgcn_global_load_lds(                                           \
        (const __attribute__((address_space(1))) void*)src_,                    \
        (__attribute__((address_space(3))) void*)dst_, 16, 0, 0);               \
  }                                                                             \
} while (0)

#define PHASE(c, KK, JH, STAGE_STMT, VM_STMT) do {                              \
  if ((JH) == 0) {                                                              \
    _Pragma("unroll")                                                           \
    for (int i_ = 0; i_ < 8; ++i_) {                                            \
      int rr_ = wm + i_ * 16 + lrow;                                            \
      int sp_ = cg ^ ((rr_ >> 1) & 3);                                          \
      afr[i_] = *(const bf16x8*)(smem + ((c) * 4 + 0 * 2 + (KK)) * 16384 + rr_ * 64 + sp_ * 16); \
    }                                                                           \
  }                                                                             \
  {                                                                             \
    int rb0_ = wn + ((JH) * 2) * 16 + lrow;                                     \
    int sb0_ = cg ^ ((rb0_ >> 1) & 3);                                          \
    bfr0 = *(const bf16x8*)(smem + ((c) * 4 + 2 + (KK)) * 16384 + rb0_ * 64 + sb0_ * 16); \
    int rb1_ = wn + ((JH) * 2 + 1) * 16 + lrow;                                 \
    int sb1_ = cg ^ ((rb1_ >> 1) & 3);                                          \
    bfr1 = *(const bf16x8*)(smem + ((c) * 4 + 2 + (KK)) * 16384 + rb1_ * 64 + sb1_ * 16); \
  }                                                                             \
  STAGE_STMT;                                                                   \
  BARR();                                                                       \
  asm volatile("s_waitcnt lgkmcnt(0)" ::: "memory");                            \
  __builtin_amdgcn_sched_barrier(0);                                            \
  __builtin_amdgcn_s_setprio(1);                                                \
  _Pragma("unroll")                                                             \
  for (int i_ = 0; i_ < 8; ++i_) {                                              \
    acc[i_][(JH) * 2]     = __builtin_amdgcn_mfma_f32_16x16x32_bf16(afr[i_], bfr0, acc[i_][(JH) * 2], 0, 0, 0);     \
    acc[i_][(JH) * 2 + 1] = __builtin_amdgcn_mfma_f32_16x16x32_bf16(afr[i_], bfr1, acc[i_][(JH) * 2 + 1], 0, 0, 0); \
  }                                                                             \
  __builtin_amdgcn_s_setprio(0);                                                \
  VM_STMT;                                                                      \
  BARR();                                                                       \
} while (0)

struct GSeg {
  const unsigned short* A; const unsigned short* B; float* C;
  const float* bias;
  int M, Nout, K, nMblk, blk0;
};
#define NGSEG 5
struct GSegTable { GSeg s[NGSEG]; };

__global__ __launch_bounds__(512, 2) void gemm8p(GSegTable tab)
{
  extern __shared__ char smem[];
  const int tid  = threadIdx.x;
  const int lane = tid & 63;
  const int w    = tid >> 6;
  const int lrow = lane & 15;
  const int cg   = lane >> 4;
  const int sr0  = w * 16 + (lane >> 2);
  const int ssp  = lane & 3;

  const int nwg = gridDim.x;
  const int id  = blockIdx.x;
  const int q = nwg >> 3, r = nwg & 7;
  const int xcd = id & 7, lo = id >> 3;
  const int wgid = (xcd < r ? xcd * (q + 1) : r * (q + 1) + (xcd - r) * q) + lo;

  int si = 0;
#pragma unroll
  for (int i = 1; i < NGSEG; ++i) si += (wgid >= tab.s[i].blk0);
  const GSeg sg = tab.s[si];
  const int lwg = wgid - sg.blk0;
  const int mb = lwg % sg.nMblk;
  const int nb = lwg / sg.nMblk;
  const int M = sg.M, Nout = sg.Nout, K = sg.K;
  const unsigned short* __restrict__ Ap = sg.A;
  const unsigned short* __restrict__ Bw = sg.B;
  float* __restrict__ C = sg.C;
  const float* __restrict__ bias = sg.bias;

  const int m0 = mb * 256;
  const int n0 = nb * 256;
  const int wm = (w >> 2) * 128;
  const int wn = (w & 3) * 64;

  f32x4 acc[8][4];
#pragma unroll
  for (int i = 0; i < 8; ++i)
#pragma unroll
    for (int j = 0; j < 4; ++j) acc[i][j] = f32x4{0.f, 0.f, 0.f, 0.f};
  bf16x8 afr[8];
  bf16x8 bfr0, bfr1;

  const int NT = K >> 6;  // >= 3

  STAGE_UNIT(0, 0, 0, 0);
  STAGE_UNIT(0, 1, 0, 0);
  STAGE_UNIT(0, 0, 1, 0);
  STAGE_UNIT(0, 1, 1, 0);
  STAGE_UNIT(1, 0, 0, 1);
  STAGE_UNIT(1, 1, 0, 1);
  VM8();
  BARR();

  for (int kt = 0; kt < NT - 2; ++kt) {
    const int c = kt & 1;
    PHASE(c, 0, 0, STAGE_UNIT(c ^ 1, 0, 1, kt + 1), ;);
    PHASE(c, 0, 1, STAGE_UNIT(c ^ 1, 1, 1, kt + 1), VM8(););
    PHASE(c, 1, 0, STAGE_UNIT(c,     0, 0, kt + 2), ;);
    PHASE(c, 1, 1, STAGE_UNIT(c,     1, 0, kt + 2), VM8(););
  }
  {
    const int kt = NT - 2;
    const int c = kt & 1;
    PHASE(c, 0, 0, STAGE_UNIT(c ^ 1, 0, 1, kt + 1), ;);
    PHASE(c, 0, 1, STAGE_UNIT(c ^ 1, 1, 1, kt + 1), VM8(););
    PHASE(c, 1, 0, ;, ;);
    PHASE(c, 1, 1, ;, VM4(););
  }
  {
    const int c = (NT - 1) & 1;
    PHASE(c, 0, 0, ;, ;);
    PHASE(c, 0, 1, ;, VM0(););
    PHASE(c, 1, 0, ;, ;);
    PHASE(c, 1, 1, ;, ;);
  }

#pragma unroll
  for (int i = 0; i < 8; ++i) {
    int row0 = m0 + wm + i * 16 + (lane >> 4) * 4;
#pragma unroll
    for (int j = 0; j < 4; ++j) {
      int col = n0 + wn + j * 16 + (lane & 15);
      if (col < Nout) {
        float badd = bias ? bias[col] : 0.f;
#pragma unroll
        for (int r2 = 0; r2 < 4; ++r2) {
          int row = row0 + r2;
          if (row < M) C[(size_t)row * Nout + col] = acc[i][j][r2] + badd;
        }
      }
    }
  }
}

// ---------------- E2: s_t = sigmoid(xs + hs) * tanh(cells) -> bf16 ----------------
__global__ void k_st(const float* __restrict__ XS, const float* __restrict__ HS,
                     const float* __restrict__ cells, unsigned short* __restrict__ stbf, int n) {
  int i = blockIdx.x * blockDim.x + threadIdx.x;
  int stride = gridDim.x * blockDim.x;
  for (; i < n; i += stride) {
    float pre = XS[i] + HS[i];
    float v = fast_sigmoid(pre) * fast_tanh(cells[i]);
    stbf[i] = f2bf(v);
  }
}

// ---------------- E3: switch softmax + V ----------------
__global__ __launch_bounds__(256) void k_switch(
    const float* __restrict__ AH, const float* __restrict__ AG,
    const float* __restrict__ q, const float* __restrict__ wsw,
    const float* __restrict__ H, const float* __restrict__ G,
    unsigned short* __restrict__ Vbf, float* __restrict__ sw_out)
{
  int bl = blockIdx.x;
  int b = bl / LL;
  int tid = threadIdx.x;
  float aH = 0.f, aG = 0.f;
  for (int h = tid; h < HID; h += 256) {
    float qv = q[b * HID + h], w = wsw[h];
    aH += fast_tanh(AH[(size_t)bl * HID + h] + qv) * w;
    aG += fast_tanh(AG[(size_t)bl * HID + h] + qv) * w;
  }
#pragma unroll
  for (int off = 32; off > 0; off >>= 1) {
    aH += __shfl_down(aH, off);
    aG += __shfl_down(aG, off);
  }
  __shared__ float redH[4], redG[4];
  int lane = tid & 63, wave = tid >> 6;
  if (lane == 0) { redH[wave] = aH; redG[wave] = aG; }
  __syncthreads();
  float sH = redH[0] + redH[1] + redH[2] + redH[3];
  float sG = redG[0] + redG[1] + redG[2] + redG[3];
  float m = fmaxf(sH, sG);
  float e0 = __expf(sH - m), e1 = __expf(sG - m);
  float inv = 1.f / (e0 + e1);
  float sw0 = e0 * inv, sw1 = e1 * inv;
  if (tid == 0) { sw_out[bl * 2] = sw0; sw_out[bl * 2 + 1] = sw1; }
  for (int h = tid; h < HID; h += 256) {
    float v = sw0 * H[(size_t)bl * HID + h] + sw1 * G[(size_t)bl * HID + h];
    Vbf[(size_t)bl * HID + h] = f2bf(v);
  }
}

// ---------------- E4: z_t/z_s -> alpha/beta -> c_hat+hiddens ----------------
__global__ __launch_bounds__(256) void k_attn(
    const float* __restrict__ PV, const float* __restrict__ PG,
    const float* __restrict__ SS, const float* __restrict__ wh,
    const unsigned short* __restrict__ stbf, const unsigned short* __restrict__ Vbf,
    const float* __restrict__ hiddens,
    float* __restrict__ alpha_out, float* __restrict__ beta_out,
    unsigned short* __restrict__ chh)
{
  const int TG = 4;
  int b  = blockIdx.x / (TT / TG);
  int t0 = (blockIdx.x % (TT / TG)) * TG;
  int tid = threadIdx.x;
  __shared__ float pg_s[TG][LL], wh_s[LL], zz[TG][LL + 1], alpha_s[TG][LL], beta_sh[TG];

  if (tid < LL) wh_s[tid] = wh[tid];
  if (tid < TG * LL) {
    int tt = tid / LL, k = tid - tt * LL;
    pg_s[tt][k] = PG[(size_t)(b * TT + t0 + tt) * 64 + k];
  }
  __syncthreads();

  if (tid < TG * (LL + 1)) {
    int tt = tid / (LL + 1), l = tid - tt * (LL + 1);
    const float* src = (l < LL) ? &PV[((size_t)b * LL + l) * 64]
                                : &SS[(size_t)(b * TT + t0 + tt) * 64];
    float acc = 0.f;
    for (int k = 0; k < LL; ++k) acc += fast_tanh(src[k] + pg_s[tt][k]) * wh_s[k];
    zz[tt][l] = acc;
  }
  __syncthreads();

  if (tid < TG) {
    int tt = tid, bt = b * TT + t0 + tt;
    float mx = -1e30f;
    for (int l = 0; l < LL; ++l) mx = fmaxf(mx, zz[tt][l]);
    float sum = 0.f;
    for (int l = 0; l < LL; ++l) { float e = __expf(zz[tt][l] - mx); alpha_s[tt][l] = e; sum += e; }
    float inv = 1.f / sum;
    for (int l = 0; l < LL; ++l) {
      alpha_s[tt][l] *= inv;
      alpha_out[(size_t)bt * LL + l] = alpha_s[tt][l];
    }
    float mx2 = fmaxf(mx, zz[tt][LL]);
    float s2 = 0.f;
    for (int l = 0; l <= LL; ++l) s2 += __expf(zz[tt][l] - mx2);
    float bet = __expf(zz[tt][LL] - mx2) / s2;
    beta_sh[tt] = bet;
    beta_out[bt] = bet;
  }
  __syncthreads();

  for (int h = tid; h < HID; h += 256) {
    float ct[TG] = {0.f, 0.f, 0.f, 0.f};
    for (int l = 0; l < LL; ++l) {
      float v = bf2f(Vbf[((size_t)b * LL + l) * HID + h]);
#pragma unroll
      for (int tt = 0; tt < TG; ++tt) ct[tt] += alpha_s[tt][l] * v;
    }
#pragma unroll
    for (int tt = 0; tt < TG; ++tt) {
      int bt = b * TT + t0 + tt;
      float bet = beta_sh[tt];
      float s = bf2f(stbf[(size_t)bt * HID + h]);
      float chat = bet * s + (1.f - bet) * ct[tt];
      chh[(size_t)bt * HID + h] = f2bf(chat + hiddens[(size_t)bt * HID + h]);
    }
  }
}

// ---------------- launcher ----------------
static inline int nblk(long n) {
  long g = (n + 255) / 256;
  if (g > 8192) g = 8192;
  return (int)g;
}

extern "C" void kernel_launch(void* const* d_in, const int* in_sizes, int n_in,
                              void* d_out, int out_size, void* d_ws, size_t ws_size,
                              hipStream_t stream)
{
  const float* x       = (const float*)d_in[0];
  const float* hiddens = (const float*)d_in[1];
  const float* cells   = (const float*)d_in[2];
  const float* G       = (const float*)d_in[3];
  const float* H       = (const float*)d_in[4];
  const float* W_sx    = (const float*)d_in[5];
  const float* W_sh    = (const float*)d_in[6];
  const float* W_ax    = (const float*)d_in[7];
  const float* W_ah    = (const float*)d_in[8];
  const float* W_ag    = (const float*)d_in[9];
  const float* w_sw    = (const float*)d_in[10];
  const float* Wv      = (const float*)d_in[11];
  const float* Wg      = (const float*)d_in[12];
  const float* Ws      = (const float*)d_in[13];
  const float* wh      = (const float*)d_in[14];
  const float* W_mlp   = (const float*)d_in[15];
  const float* b_mlp   = (const float*)d_in[16];

  float* scores = (float*)d_out;
  float* alpha  = scores + (size_t)BT * VOC;
  float* beta   = alpha + (size_t)BT * LL;
  float* swout  = beta + BT;

  char* wsp = (char*)d_ws;
  size_t off = 0;
  auto alloc = [&](size_t bytes) -> char* {
    char* p = wsp + off;
    off += (bytes + 255) & ~(size_t)255;
    return p;
  };

  unsigned short* xbf    = (unsigned short*)alloc((size_t)BT * E2 * 2);
  unsigned short* wsa    = (unsigned short*)alloc((size_t)E2 * E2 * 2);  // [W_sx; W_ax]
  unsigned short* hprev  = (unsigned short*)alloc((size_t)BT * HID * 2);
  unsigned short* wshb   = (unsigned short*)alloc((size_t)HID * HID * 2);
  unsigned short* wahb   = (unsigned short*)alloc((size_t)HID * HID * 2);
  unsigned short* wagb   = (unsigned short*)alloc((size_t)HID * HID * 2);
  unsigned short* Hbf    = (unsigned short*)alloc((size_t)BL * HID * 2);
  unsigned short* Gbf    = (unsigned short*)alloc((size_t)BL * HID * 2);
  unsigned short* hidbf  = (unsigned short*)alloc((size_t)BT * HID * 2);
  unsigned short* wvb    = (unsigned short*)alloc((size_t)NPAD_S * HID * 2);
  unsigned short* wgb    = (unsigned short*)alloc((size_t)NPAD_S * HID * 2);
  unsigned short* wsb    = (unsigned short*)alloc((size_t)NPAD_S * HID * 2);
  unsigned short* wmlpb  = (unsigned short*)alloc((size_t)NPAD_MLP * HID * 2);
  unsigned short* Vbf    = (unsigned short*)alloc((size_t)BL * HID * 2);
  unsigned short* stbf   = (unsigned short*)alloc((size_t)BT * HID * 2);
  unsigned short* chh    = (unsigned short*)alloc((size_t)BT * HID * 2);
  unsigned short* xmbf   = (unsigned short*)alloc((size_t)BB * E2 * 2);
  float* XS = (float*)alloc((size_t)BT * HID * 4);
  float* HS = (float*)alloc((size_t)BT * HID * 4);
  float* AH = (float*)alloc((size_t)BL * HID * 4);
  float* AG = (float*)alloc((size_t)BL * HID * 4);
  float* qb = (float*)alloc((size_t)BB * HID * 4);
  float* PV = (float*)alloc((size_t)BL * 64 * 4);
  float* PG = (float*)alloc((size_t)BT * 64 * 4);
  float* SS = (float*)alloc((size_t)BT * 64 * 4);
  (void)ws_size; (void)in_sizes; (void)n_in; (void)out_size;

  // --- 1: fused converts ---
  SegTable tab;
  int blk = 0, si = 0;
  auto seg = [&](const float* s, unsigned short* d, int n4, int nrows, int mode) {
    tab.s[si].src = s; tab.s[si].dst = d; tab.s[si].n4 = n4;
    tab.s[si].nrows = nrows; tab.s[si].mode = mode; tab.s[si].blk0 = blk;
    blk += (n4 + CHUNK4 - 1) / CHUNK4; ++si;
  };
  seg(W_sx, wsa,                        HID * E2 / 4, 0, 0);
  seg(W_ax, wsa + (size_t)HID * E2,     HID * E2 / 4, 0, 0);
  seg(x, xbf,                           BT * E2 / 4, 0, 0);
  seg(hiddens, hprev,                   BT * HID / 4, 0, 2);
  seg(W_sh, wshb,                       HID * HID / 4, 0, 0);
  seg(W_ah, wahb,                       HID * HID / 4, 0, 0);
  seg(W_ag, wagb,                       HID * HID / 4, 0, 0);
  seg(H, Hbf,                           BL * HID / 4, 0, 0);
  seg(G, Gbf,                           BL * HID / 4, 0, 0);
  seg(hiddens, hidbf,                   BT * HID / 4, 0, 0);
  seg(Wv, wvb,                          NPAD_S * HID / 4, LL, 1);
  seg(Wg, wgb,                          NPAD_S * HID / 4, LL, 1);
  seg(Ws, wsb,                          NPAD_S * HID / 4, LL, 1);
  seg(W_mlp, wmlpb,                     NPAD_MLP * HID / 4, VOC, 1);
  k_convall<<<blk, 256, 0, stream>>>(tab);

  // --- 2: x time-mean (for q) ---
  k_xmean<<<BB * 6, 256, 0, stream>>>(x, xmbf);

  // --- 3: mega 8-phase GEMM dispatch: xs, sh, ah, ag, q ---
  GSegTable gt;
  int gblk = 0, gi = 0;
  auto gseg = [&](const unsigned short* A, const unsigned short* B, float* C,
                  const float* bias, int M, int N, int K, int nMblk, int nNblk) {
    gt.s[gi].A = A; gt.s[gi].B = B; gt.s[gi].C = C; gt.s[gi].bias = bias;
    gt.s[gi].M = M; gt.s[gi].Nout = N; gt.s[gi].K = K; gt.s[gi].nMblk = nMblk;
    gt.s[gi].blk0 = gblk;
    gblk += nMblk * nNblk; ++gi;
  };
  gseg(xbf,   wsa,                      XS, nullptr, BT, HID, E2,  15, 3);
  gseg(hprev, wshb,                     HS, nullptr, BT, HID, HID, 15, 3);
  gseg(Hbf,   wahb,                     AH, nullptr, BL, HID, HID, 13, 3);
  gseg(Gbf,   wagb,                     AG, nullptr, BL, HID, HID, 13, 3);
  gseg(xmbf,  wsa + (size_t)HID * E2,   qb, nullptr, BB, HID, E2,  1,  3);
  gemm8p<<<gblk, 512, 131072, stream>>>(gt);

  // --- 4/5: gate + switch ---
  k_st<<<nblk((long)BT * HID), 256, 0, stream>>>(XS, HS, cells, stbf, BT * HID);
  k_switch<<<BL, 256, 0, stream>>>(AH, AG, qb, w_sw, H, G, Vbf, swout);

  // --- 6: skinny GEMMs (one segmented dispatch) ---
  SSegTable st;
  st.s[0] = SSeg{Vbf,   wvb, PV, BL, 64, HID, 25, 0};
  st.s[1] = SSeg{hidbf, wgb, PG, BT, 64, HID, 30, 25};
  st.s[2] = SSeg{stbf,  wsb, SS, BT, 64, HID, 30, 55};
  gemm_bt_seg<<<85, 256, 0, stream>>>(st);

  // --- 7: attention epilogue ---
  k_attn<<<BB * (TT / 4), 256, 0, stream>>>(PV, PG, SS, wh, stbf, Vbf, hiddens,
                                            alpha, beta, chh);

  // --- 8: scores GEMM (256^2 8-phase, +bias) ---
  GSegTable gs;
  for (int i = 0; i < NGSEG; ++i) { gs.s[i] = gt.s[i]; gs.s[i].blk0 = 0x7fffffff; }
  gs.s[0] = GSeg{chh, wmlpb, scores, b_mlp, BT, VOC, HID, 15, 0};
  gemm8p<<<15 * 40, 512, 131072, stream>>>(gs);
}

// Round 5
// 311.307 us; speedup vs baseline: 1.6337x; 1.0044x over previous
//
#include <hip/hip_runtime.h>

#define BB 64
#define TT 60
#define LL 49
#define HID 768
#define E2 1536
#define VOC 10000
#define BT (BB*TT)      // 3840
#define BL (BB*LL)      // 3136
#define NPAD_MLP 10240  // 40*256
#define NPAD_S 128

typedef __bf16 bf16x8 __attribute__((ext_vector_type(8)));
typedef float f32x4 __attribute__((ext_vector_type(4)));

__device__ __forceinline__ unsigned short f2bf(float f) {
  union { float f; unsigned int u; } v; v.f = f;
  unsigned int u = v.u;
  return (unsigned short)((u + 0x7fffu + ((u >> 16) & 1u)) >> 16);  // RNE
}
__device__ __forceinline__ float bf2f(unsigned short h) {
  union { unsigned int u; float f; } v; v.u = ((unsigned int)h) << 16;
  return v.f;
}
__device__ __forceinline__ float fast_tanh(float x) {
  float e = __expf(2.f * x);
  return 1.f - 2.f / (e + 1.f);
}
__device__ __forceinline__ float fast_sigmoid(float x) {
  return 1.f / (1.f + __expf(-x));
}

// ---------------- fused convert: all fp32->bf16 staging in ONE kernel ----------------
#define NSEG 14
#define CHUNK4 2048
struct SegT {
  const float* src;
  unsigned short* dst;
  int n4;
  int nrows;
  int mode;    // 0 plain, 1 pad-rows, 2 timestep-shift
  int blk0;
};
struct SegTable { SegT s[NSEG]; };

__global__ __launch_bounds__(256) void k_convall(SegTable tab) {
  int b = blockIdx.x;
  int si = 0;
#pragma unroll
  for (int i = 1; i < NSEG; ++i) si += (b >= tab.s[i].blk0);
  SegT sg = tab.s[si];
  int lb = b - sg.blk0;
  int end = (lb + 1) * CHUNK4; end = end < sg.n4 ? end : sg.n4;
  for (int i = lb * CHUNK4 + threadIdx.x; i < end; i += 256) {
    ushort4 o; o.x = o.y = o.z = o.w = 0;
    if (sg.mode == 0) {
      float4 v = ((const float4*)sg.src)[i];
      o.x = f2bf(v.x); o.y = f2bf(v.y); o.z = f2bf(v.z); o.w = f2bf(v.w);
    } else if (sg.mode == 1) {
      int row = i / 192;
      if (row < sg.nrows) {
        float4 v = ((const float4*)sg.src)[i];
        o.x = f2bf(v.x); o.y = f2bf(v.y); o.z = f2bf(v.z); o.w = f2bf(v.w);
      }
    } else {
      int bt = i / 192;
      if (bt % TT != 0) {
        float4 v = ((const float4*)sg.src)[i - 192];
        o.x = f2bf(v.x); o.y = f2bf(v.y); o.z = f2bf(v.z); o.w = f2bf(v.w);
      }
    }
    ((ushort4*)sg.dst)[i] = o;
  }
}

// ---------------- k_xmean: xm[b,c] = bf16(mean_t x[b,t,c]) ----------------
__global__ __launch_bounds__(256) void k_xmean(const float* __restrict__ x,
                                               unsigned short* __restrict__ xm) {
  int b = blockIdx.x / 6;
  int c = (blockIdx.x % 6) * 256 + threadIdx.x;
  float s = 0.f;
  for (int t = 0; t < TT; ++t) s += x[((size_t)b * TT + t) * E2 + c];
  xm[(size_t)b * E2 + c] = f2bf(s * (1.f / 60.f));
}

// ---------------- segmented 128^2 2-phase GEMM (skinny N=64 GEMMs) ----------------
struct SSeg {
  const unsigned short* A; const unsigned short* B; float* C;
  int M, Nout, K, nMblk, blk0;
};
#define NSSEG 3
struct SSegTable { SSeg s[NSSEG]; };

__global__ __launch_bounds__(256) void gemm_bt_seg(SSegTable tab)
{
  __shared__ __attribute__((aligned(16))) unsigned short As[128*32];
  __shared__ __attribute__((aligned(16))) unsigned short Bs[128*32];
  const int tid  = threadIdx.x;
  const int lane = tid & 63;
  const int wave = tid >> 6;

  const int nwg = gridDim.x;
  const int id  = blockIdx.x;
  const int q = nwg >> 3, r = nwg & 7;
  const int xcd = id & 7, lo = id >> 3;
  const int wgid = (xcd < r ? xcd * (q + 1) : r * (q + 1) + (xcd - r) * q) + lo;

  int si = 0;
#pragma unroll
  for (int i = 1; i < NSSEG; ++i) si += (wgid >= tab.s[i].blk0);
  const SSeg sg = tab.s[si];
  const int lwg = wgid - sg.blk0;
  const int mb = lwg % sg.nMblk;
  const int nb = lwg / sg.nMblk;
  const int M = sg.M, Nout = sg.Nout, K = sg.K;
  const unsigned short* __restrict__ A  = sg.A;
  const unsigned short* __restrict__ Bw = sg.B;
  float* __restrict__ C = sg.C;
  const int m0 = mb * 128;
  const int n0 = nb * 128;
  const int wm = (wave >> 1) * 64;
  const int wn = (wave & 1) * 64;

  f32x4 acc[4][4];
#pragma unroll
  for (int i = 0; i < 4; ++i)
#pragma unroll
    for (int j = 0; j < 4; ++j) acc[i][j] = f32x4{0.f, 0.f, 0.f, 0.f};

  const int lrow = lane & 15;
  const int kb   = (lane >> 4) * 8;

  for (int k0 = 0; k0 < K; k0 += 32) {
    __syncthreads();
#pragma unroll
    for (int p = 0; p < 2; ++p) {
      int slot = p * 256 + wave * 64 + lane;
      int row = slot >> 2, c8 = slot & 3;
      int ar = m0 + row; ar = ar < M ? ar : (M - 1);
      const unsigned short* asrc = A + (size_t)ar * K + k0 + c8 * 8;
      __builtin_amdgcn_global_load_lds(
          (const __attribute__((address_space(1))) void*)asrc,
          (__attribute__((address_space(3))) void*)&As[(p * 256 + wave * 64) * 8],
          16, 0, 0);
      const unsigned short* bsrc = Bw + (size_t)(n0 + row) * K + k0 + c8 * 8;
      __builtin_amdgcn_global_load_lds(
          (const __attribute__((address_space(1))) void*)bsrc,
          (__attribute__((address_space(3))) void*)&Bs[(p * 256 + wave * 64) * 8],
          16, 0, 0);
    }
    __syncthreads();

    bf16x8 av[4], bv[4];
#pragma unroll
    for (int i = 0; i < 4; ++i)
      av[i] = *(const bf16x8*)&As[(wm + i * 16 + lrow) * 32 + kb];
#pragma unroll
    for (int j = 0; j < 4; ++j)
      bv[j] = *(const bf16x8*)&Bs[(wn + j * 16 + lrow) * 32 + kb];
#pragma unroll
    for (int i = 0; i < 4; ++i)
#pragma unroll
      for (int j = 0; j < 4; ++j)
        acc[i][j] = __builtin_amdgcn_mfma_f32_16x16x32_bf16(av[i], bv[j], acc[i][j], 0, 0, 0);
  }

  const int cr = (lane >> 4) * 4;
  const int cc = lane & 15;
#pragma unroll
  for (int i = 0; i < 4; ++i) {
    int row0 = m0 + wm + i * 16 + cr;
#pragma unroll
    for (int j = 0; j < 4; ++j) {
      int col = n0 + wn + j * 16 + cc;
      if (col < Nout) {
#pragma unroll
        for (int r2 = 0; r2 < 4; ++r2) {
          int row = row0 + r2;
          if (row < M) C[(size_t)row * Nout + col] = acc[i][j][r2];
        }
      }
    }
  }
}

// ---------------- segmented 256^2 pipelined GEMM, BK=32, 64KB LDS (2 blk/CU) ----------------
// Per segment: M arbitrary (A-rows clamped, stores guarded); B zero-padded to
// nNblk*256 rows; K % 32 == 0, K/32 >= 3.
// LDS: buf c in {0,1}: A panel (256x32 bf16, 16KB) at c*32768, B panel at +16384.
// Swizzle: 16B-slot s' = s ^ ((row>>1)&3) on stage SOURCE and ds_read (involution).
// Staging (2-deep, dead-panel-safe): S_B(t+1) in JH0(t); S_A(t+2) in JH1(t);
// counted vmcnt(2) at end of each K-tile (never 0 mid-loop).
#define BARR() do { asm volatile("" ::: "memory"); __builtin_amdgcn_s_barrier(); \
                    asm volatile("" ::: "memory"); } while (0)
#define VM2() asm volatile("s_waitcnt vmcnt(2)" ::: "memory")
#define VM0() asm volatile("s_waitcnt vmcnt(0)" ::: "memory")

#define STAGE_OP(ct, op, kt) do {                                               \
  int k0_ = (kt) * 32;                                                          \
  _Pragma("unroll")                                                             \
  for (int l_ = 0; l_ < 2; ++l_) {                                              \
    int rr_ = l_ * 128 + sr0;                                                   \
    int ss_ = ssp ^ ((rr_ >> 1) & 3);                                           \
    int gr_ = (op) ? (n0 + rr_) : ((m0 + rr_) < M ? (m0 + rr_) : (M - 1));      \
    const unsigned short* src_ = ((op) ? Bw : Ap) + (size_t)gr_ * K + k0_ + ss_ * 8; \
    char* dst_ = smem + (ct) * 32768 + (op) * 16384 + l_ * 8192 + w * 1024;     \
    __builtin_amdgcn_global_load_lds(                                           \
        (const __attribute__((address_space(1))) void*)src_,                    \
        (__attribute__((address_space(3))) void*)dst_, 16, 0, 0);               \
  }                                                                             \
} while (0)

#define PHASE(c, JH, STAGE_STMT, VM_STMT) do {                                  \
  if ((JH) == 0) {                                                              \
    _Pragma("unroll")                                                           \
    for (int i_ = 0; i_ < 8; ++i_) {                                            \
      int rr_ = wm + i_ * 16 + lrow;                                            \
      int sp_ = cg ^ ((rr_ >> 1) & 3);                                          \
      afr[i_] = *(const bf16x8*)(smem + (c) * 32768 + rr_ * 64 + sp_ * 16);     \
    }                                                                           \
  }                                                                             \
  {                                                                             \
    int rb0_ = wn + ((JH) * 2) * 16 + lrow;                                     \
    int sb0_ = cg ^ ((rb0_ >> 1) & 3);                                          \
    bfr0 = *(const bf16x8*)(smem + (c) * 32768 + 16384 + rb0_ * 64 + sb0_ * 16); \
    int rb1_ = wn + ((JH) * 2 + 1) * 16 + lrow;                                 \
    int sb1_ = cg ^ ((rb1_ >> 1) & 3);                                          \
    bfr1 = *(const bf16x8*)(smem + (c) * 32768 + 16384 + rb1_ * 64 + sb1_ * 16); \
  }                                                                             \
  STAGE_STMT;                                                                   \
  BARR();                                                                       \
  asm volatile("s_waitcnt lgkmcnt(0)" ::: "memory");                            \
  __builtin_amdgcn_sched_barrier(0);                                            \
  __builtin_amdgcn_s_setprio(1);                                                \
  _Pragma("unroll")                                                             \
  for (int i_ = 0; i_ < 8; ++i_) {                                              \
    acc[i_][(JH) * 2]     = __builtin_amdgcn_mfma_f32_16x16x32_bf16(afr[i_], bfr0, acc[i_][(JH) * 2], 0, 0, 0);     \
    acc[i_][(JH) * 2 + 1] = __builtin_amdgcn_mfma_f32_16x16x32_bf16(afr[i_], bfr1, acc[i_][(JH) * 2 + 1], 0, 0, 0); \
  }                                                                             \
  __builtin_amdgcn_s_setprio(0);                                                \
  VM_STMT;                                                                      \
  BARR();                                                                       \
} while (0)

struct GSeg {
  const unsigned short* A; const unsigned short* B; float* C;
  const float* bias;
  int M, Nout, K, nMblk, blk0;
};
#define NGSEG 5
struct GSegTable { GSeg s[NGSEG]; };

__global__ __launch_bounds__(512, 2) void gemm8p(GSegTable tab)
{
  extern __shared__ char smem[];
  const int tid  = threadIdx.x;
  const int lane = tid & 63;
  const int w    = tid >> 6;
  const int lrow = lane & 15;
  const int cg   = lane >> 4;
  const int sr0  = w * 16 + (lane >> 2);
  const int ssp  = lane & 3;

  const int nwg = gridDim.x;
  const int id  = blockIdx.x;
  const int q = nwg >> 3, r = nwg & 7;
  const int xcd = id & 7, lo = id >> 3;
  const int wgid = (xcd < r ? xcd * (q + 1) : r * (q + 1) + (xcd - r) * q) + lo;

  int si = 0;
#pragma unroll
  for (int i = 1; i < NGSEG; ++i) si += (wgid >= tab.s[i].blk0);
  const GSeg sg = tab.s[si];
  const int lwg = wgid - sg.blk0;
  const int mb = lwg % sg.nMblk;
  const int nb = lwg / sg.nMblk;
  const int M = sg.M, Nout = sg.Nout, K = sg.K;
  const unsigned short* __restrict__ Ap = sg.A;
  const unsigned short* __restrict__ Bw = sg.B;
  float* __restrict__ C = sg.C;
  const float* __restrict__ bias = sg.bias;

  const int m0 = mb * 256;
  const int n0 = nb * 256;
  const int wm = (w >> 2) * 128;
  const int wn = (w & 3) * 64;

  f32x4 acc[8][4];
#pragma unroll
  for (int i = 0; i < 8; ++i)
#pragma unroll
    for (int j = 0; j < 4; ++j) acc[i][j] = f32x4{0.f, 0.f, 0.f, 0.f};
  bf16x8 afr[8];
  bf16x8 bfr0, bfr1;

  const int NT = K >> 5;  // K/32, >= 3

  // prologue: tile0 A+B, tile1 A; wait tile0 (leave tile1-A in flight)
  STAGE_OP(0, 0, 0);
  STAGE_OP(0, 1, 0);
  STAGE_OP(1, 0, 1);
  VM2();
  BARR();

  for (int kt = 0; kt < NT - 2; ++kt) {
    const int c = kt & 1;
    PHASE(c, 0, STAGE_OP(c ^ 1, 1, kt + 1), ;);       // B(t+1): panel dead since JH1(t-1)
    PHASE(c, 1, STAGE_OP(c, 0, kt + 2), VM2(););      // A(t+2): panel dead after JH0(t)
  }
  {
    const int kt = NT - 2;
    const int c = kt & 1;
    PHASE(c, 0, STAGE_OP(c ^ 1, 1, NT - 1), ;);
    PHASE(c, 1, ;, VM0(););
  }
  {
    const int c = (NT - 1) & 1;
    PHASE(c, 0, ;, ;);
    PHASE(c, 1, ;, ;);
  }

  // epilogue: C/D layout col=lane&15, row=(lane>>4)*4+reg
#pragma unroll
  for (int i = 0; i < 8; ++i) {
    int row0 = m0 + wm + i * 16 + (lane >> 4) * 4;
#pragma unroll
    for (int j = 0; j < 4; ++j) {
      int col = n0 + wn + j * 16 + (lane & 15);
      if (col < Nout) {
        float badd = bias ? bias[col] : 0.f;
#pragma unroll
        for (int r2 = 0; r2 < 4; ++r2) {
          int row = row0 + r2;
          if (row < M) C[(size_t)row * Nout + col] = acc[i][j][r2] + badd;
        }
      }
    }
  }
}

// ---------------- E2: s_t = sigmoid(xs + hs) * tanh(cells) -> bf16 ----------------
__global__ void k_st(const float* __restrict__ XS, const float* __restrict__ HS,
                     const float* __restrict__ cells, unsigned short* __restrict__ stbf, int n) {
  int i = blockIdx.x * blockDim.x + threadIdx.x;
  int stride = gridDim.x * blockDim.x;
  for (; i < n; i += stride) {
    float pre = XS[i] + HS[i];
    float v = fast_sigmoid(pre) * fast_tanh(cells[i]);
    stbf[i] = f2bf(v);
  }
}

// ---------------- E3: switch softmax + V ----------------
__global__ __launch_bounds__(256) void k_switch(
    const float* __restrict__ AH, const float* __restrict__ AG,
    const float* __restrict__ q, const float* __restrict__ wsw,
    const float* __restrict__ H, const float* __restrict__ G,
    unsigned short* __restrict__ Vbf, float* __restrict__ sw_out)
{
  int bl = blockIdx.x;
  int b = bl / LL;
  int tid = threadIdx.x;
  float aH = 0.f, aG = 0.f;
  for (int h = tid; h < HID; h += 256) {
    float qv = q[b * HID + h], w = wsw[h];
    aH += fast_tanh(AH[(size_t)bl * HID + h] + qv) * w;
    aG += fast_tanh(AG[(size_t)bl * HID + h] + qv) * w;
  }
#pragma unroll
  for (int off = 32; off > 0; off >>= 1) {
    aH += __shfl_down(aH, off);
    aG += __shfl_down(aG, off);
  }
  __shared__ float redH[4], redG[4];
  int lane = tid & 63, wave = tid >> 6;
  if (lane == 0) { redH[wave] = aH; redG[wave] = aG; }
  __syncthreads();
  float sH = redH[0] + redH[1] + redH[2] + redH[3];
  float sG = redG[0] + redG[1] + redG[2] + redG[3];
  float m = fmaxf(sH, sG);
  float e0 = __expf(sH - m), e1 = __expf(sG - m);
  float inv = 1.f / (e0 + e1);
  float sw0 = e0 * inv, sw1 = e1 * inv;
  if (tid == 0) { sw_out[bl * 2] = sw0; sw_out[bl * 2 + 1] = sw1; }
  for (int h = tid; h < HID; h += 256) {
    float v = sw0 * H[(size_t)bl * HID + h] + sw1 * G[(size_t)bl * HID + h];
    Vbf[(size_t)bl * HID + h] = f2bf(v);
  }
}

// ---------------- E4: z_t/z_s -> alpha/beta -> c_hat+hiddens ----------------
__global__ __launch_bounds__(256) void k_attn(
    const float* __restrict__ PV, const float* __restrict__ PG,
    const float* __restrict__ SS, const float* __restrict__ wh,
    const unsigned short* __restrict__ stbf, const unsigned short* __restrict__ Vbf,
    const float* __restrict__ hiddens,
    float* __restrict__ alpha_out, float* __restrict__ beta_out,
    unsigned short* __restrict__ chh)
{
  const int TG = 4;
  int b  = blockIdx.x / (TT / TG);
  int t0 = (blockIdx.x % (TT / TG)) * TG;
  int tid = threadIdx.x;
  __shared__ float pg_s[TG][LL], wh_s[LL], zz[TG][LL + 1], alpha_s[TG][LL], beta_sh[TG];

  if (tid < LL) wh_s[tid] = wh[tid];
  if (tid < TG * LL) {
    int tt = tid / LL, k = tid - tt * LL;
    pg_s[tt][k] = PG[(size_t)(b * TT + t0 + tt) * 64 + k];
  }
  __syncthreads();

  if (tid < TG * (LL + 1)) {
    int tt = tid / (LL + 1), l = tid - tt * (LL + 1);
    const float* src = (l < LL) ? &PV[((size_t)b * LL + l) * 64]
                                : &SS[(size_t)(b * TT + t0 + tt) * 64];
    float acc = 0.f;
    for (int k = 0; k < LL; ++k) acc += fast_tanh(src[k] + pg_s[tt][k]) * wh_s[k];
    zz[tt][l] = acc;
  }
  __syncthreads();

  if (tid < TG) {
    int tt = tid, bt = b * TT + t0 + tt;
    float mx = -1e30f;
    for (int l = 0; l < LL; ++l) mx = fmaxf(mx, zz[tt][l]);
    float sum = 0.f;
    for (int l = 0; l < LL; ++l) { float e = __expf(zz[tt][l] - mx); alpha_s[tt][l] = e; sum += e; }
    float inv = 1.f / sum;
    for (int l = 0; l < LL; ++l) {
      alpha_s[tt][l] *= inv;
      alpha_out[(size_t)bt * LL + l] = alpha_s[tt][l];
    }
    float mx2 = fmaxf(mx, zz[tt][LL]);
    float s2 = 0.f;
    for (int l = 0; l <= LL; ++l) s2 += __expf(zz[tt][l] - mx2);
    float bet = __expf(zz[tt][LL] - mx2) / s2;
    beta_sh[tt] = bet;
    beta_out[bt] = bet;
  }
  __syncthreads();

  for (int h = tid; h < HID; h += 256) {
    float ct[TG] = {0.f, 0.f, 0.f, 0.f};
    for (int l = 0; l < LL; ++l) {
      float v = bf2f(Vbf[((size_t)b * LL + l) * HID + h]);
#pragma unroll
      for (int tt = 0; tt < TG; ++tt) ct[tt] += alpha_s[tt][l] * v;
    }
#pragma unroll
    for (int tt = 0; tt < TG; ++tt) {
      int bt = b * TT + t0 + tt;
      float bet = beta_sh[tt];
      float s = bf2f(stbf[(size_t)bt * HID + h]);
      float chat = bet * s + (1.f - bet) * ct[tt];
      chh[(size_t)bt * HID + h] = f2bf(chat + hiddens[(size_t)bt * HID + h]);
    }
  }
}

// ---------------- launcher ----------------
static inline int nblk(long n) {
  long g = (n + 255) / 256;
  if (g > 8192) g = 8192;
  return (int)g;
}

extern "C" void kernel_launch(void* const* d_in, const int* in_sizes, int n_in,
                              void* d_out, int out_size, void* d_ws, size_t ws_size,
                              hipStream_t stream)
{
  const float* x       = (const float*)d_in[0];
  const float* hiddens = (const float*)d_in[1];
  const float* cells   = (const float*)d_in[2];
  const float* G       = (const float*)d_in[3];
  const float* H       = (const float*)d_in[4];
  const float* W_sx    = (const float*)d_in[5];
  const float* W_sh    = (const float*)d_in[6];
  const float* W_ax    = (const float*)d_in[7];
  const float* W_ah    = (const float*)d_in[8];
  const float* W_ag    = (const float*)d_in[9];
  const float* w_sw    = (const float*)d_in[10];
  const float* Wv      = (const float*)d_in[11];
  const float* Wg      = (const float*)d_in[12];
  const float* Ws      = (const float*)d_in[13];
  const float* wh      = (const float*)d_in[14];
  const float* W_mlp   = (const float*)d_in[15];
  const float* b_mlp   = (const float*)d_in[16];

  float* scores = (float*)d_out;
  float* alpha  = scores + (size_t)BT * VOC;
  float* beta   = alpha + (size_t)BT * LL;
  float* swout  = beta + BT;

  char* wsp = (char*)d_ws;
  size_t off = 0;
  auto alloc = [&](size_t bytes) -> char* {
    char* p = wsp + off;
    off += (bytes + 255) & ~(size_t)255;
    return p;
  };

  unsigned short* xbf    = (unsigned short*)alloc((size_t)BT * E2 * 2);
  unsigned short* wsa    = (unsigned short*)alloc((size_t)E2 * E2 * 2);  // [W_sx; W_ax]
  unsigned short* hprev  = (unsigned short*)alloc((size_t)BT * HID * 2);
  unsigned short* wshb   = (unsigned short*)alloc((size_t)HID * HID * 2);
  unsigned short* wahb   = (unsigned short*)alloc((size_t)HID * HID * 2);
  unsigned short* wagb   = (unsigned short*)alloc((size_t)HID * HID * 2);
  unsigned short* Hbf    = (unsigned short*)alloc((size_t)BL * HID * 2);
  unsigned short* Gbf    = (unsigned short*)alloc((size_t)BL * HID * 2);
  unsigned short* hidbf  = (unsigned short*)alloc((size_t)BT * HID * 2);
  unsigned short* wvb    = (unsigned short*)alloc((size_t)NPAD_S * HID * 2);
  unsigned short* wgb    = (unsigned short*)alloc((size_t)NPAD_S * HID * 2);
  unsigned short* wsb    = (unsigned short*)alloc((size_t)NPAD_S * HID * 2);
  unsigned short* wmlpb  = (unsigned short*)alloc((size_t)NPAD_MLP * HID * 2);
  unsigned short* Vbf    = (unsigned short*)alloc((size_t)BL * HID * 2);
  unsigned short* stbf   = (unsigned short*)alloc((size_t)BT * HID * 2);
  unsigned short* chh    = (unsigned short*)alloc((size_t)BT * HID * 2);
  unsigned short* xmbf   = (unsigned short*)alloc((size_t)BB * E2 * 2);
  float* XS = (float*)alloc((size_t)BT * HID * 4);
  float* HS = (float*)alloc((size_t)BT * HID * 4);
  float* AH = (float*)alloc((size_t)BL * HID * 4);
  float* AG = (float*)alloc((size_t)BL * HID * 4);
  float* qb = (float*)alloc((size_t)BB * HID * 4);
  float* PV = (float*)alloc((size_t)BL * 64 * 4);
  float* PG = (float*)alloc((size_t)BT * 64 * 4);
  float* SS = (float*)alloc((size_t)BT * 64 * 4);
  (void)ws_size; (void)in_sizes; (void)n_in; (void)out_size;

  // --- 1: fused converts ---
  SegTable tab;
  int blk = 0, si = 0;
  auto seg = [&](const float* s, unsigned short* d, int n4, int nrows, int mode) {
    tab.s[si].src = s; tab.s[si].dst = d; tab.s[si].n4 = n4;
    tab.s[si].nrows = nrows; tab.s[si].mode = mode; tab.s[si].blk0 = blk;
    blk += (n4 + CHUNK4 - 1) / CHUNK4; ++si;
  };
  seg(W_sx, wsa,                        HID * E2 / 4, 0, 0);
  seg(W_ax, wsa + (size_t)HID * E2,     HID * E2 / 4, 0, 0);
  seg(x, xbf,                           BT * E2 / 4, 0, 0);
  seg(hiddens, hprev,                   BT * HID / 4, 0, 2);
  seg(W_sh, wshb,                       HID * HID / 4, 0, 0);
  seg(W_ah, wahb,                       HID * HID / 4, 0, 0);
  seg(W_ag, wagb,                       HID * HID / 4, 0, 0);
  seg(H, Hbf,                           BL * HID / 4, 0, 0);
  seg(G, Gbf,                           BL * HID / 4, 0, 0);
  seg(hiddens, hidbf,                   BT * HID / 4, 0, 0);
  seg(Wv, wvb,                          NPAD_S * HID / 4, LL, 1);
  seg(Wg, wgb,                          NPAD_S * HID / 4, LL, 1);
  seg(Ws, wsb,                          NPAD_S * HID / 4, LL, 1);
  seg(W_mlp, wmlpb,                     NPAD_MLP * HID / 4, VOC, 1);
  k_convall<<<blk, 256, 0, stream>>>(tab);

  // --- 2: x time-mean (for q) ---
  k_xmean<<<BB * 6, 256, 0, stream>>>(x, xmbf);

  // --- 3: mega pipelined GEMM dispatch: xs, sh, ah, ag, q ---
  GSegTable gt;
  int gblk = 0, gi = 0;
  auto gseg = [&](const unsigned short* A, const unsigned short* B, float* C,
                  const float* bias, int M, int N, int K, int nMblk, int nNblk) {
    gt.s[gi].A = A; gt.s[gi].B = B; gt.s[gi].C = C; gt.s[gi].bias = bias;
    gt.s[gi].M = M; gt.s[gi].Nout = N; gt.s[gi].K = K; gt.s[gi].nMblk = nMblk;
    gt.s[gi].blk0 = gblk;
    gblk += nMblk * nNblk; ++gi;
  };
  gseg(xbf,   wsa,                      XS, nullptr, BT, HID, E2,  15, 3);
  gseg(hprev, wshb,                     HS, nullptr, BT, HID, HID, 15, 3);
  gseg(Hbf,   wahb,                     AH, nullptr, BL, HID, HID, 13, 3);
  gseg(Gbf,   wagb,                     AG, nullptr, BL, HID, HID, 13, 3);
  gseg(xmbf,  wsa + (size_t)HID * E2,   qb, nullptr, BB, HID, E2,  1,  3);
  gemm8p<<<gblk, 512, 65536, stream>>>(gt);

  // --- 4/5: gate + switch ---
  k_st<<<nblk((long)BT * HID), 256, 0, stream>>>(XS, HS, cells, stbf, BT * HID);
  k_switch<<<BL, 256, 0, stream>>>(AH, AG, qb, w_sw, H, G, Vbf, swout);

  // --- 6: skinny GEMMs (one segmented dispatch) ---
  SSegTable st;
  st.s[0] = SSeg{Vbf,   wvb, PV, BL, 64, HID, 25, 0};
  st.s[1] = SSeg{hidbf, wgb, PG, BT, 64, HID, 30, 25};
  st.s[2] = SSeg{stbf,  wsb, SS, BT, 64, HID, 30, 55};
  gemm_bt_seg<<<85, 256, 0, stream>>>(st);

  // --- 7: attention epilogue ---
  k_attn<<<BB * (TT / 4), 256, 0, stream>>>(PV, PG, SS, wh, stbf, Vbf, hiddens,
                                            alpha, beta, chh);

  // --- 8: scores GEMM (+bias), grid 15x40 = 600 ---
  GSegTable gs;
  for (int i = 0; i < NGSEG; ++i) { gs.s[i] = gt.s[i]; gs.s[i].blk0 = 0x7fffffff; }
  gs.s[0] = GSeg{chh, wmlpb, scores, b_mlp, BT, VOC, HID, 15, 0};
  gemm8p<<<15 * 40, 512, 65536, stream>>>(gs);
}

// Round 6
// 292.609 us; speedup vs baseline: 1.7381x; 1.0639x over previous
//
#include <hip/hip_runtime.h>

#define BB 64
#define TT 60
#define LL 49
#define HID 768
#define E2 1536
#define VOC 10000
#define BT (BB*TT)      // 3840
#define BL (BB*LL)      // 3136
#define NPAD_MLP 10240  // 40*256
#define NPAD_S 128

typedef __bf16 bf16x8 __attribute__((ext_vector_type(8)));
typedef float f32x4 __attribute__((ext_vector_type(4)));

__device__ __forceinline__ unsigned short f2bf(float f) {
  union { float f; unsigned int u; } v; v.f = f;
  unsigned int u = v.u;
  return (unsigned short)((u + 0x7fffu + ((u >> 16) & 1u)) >> 16);  // RNE
}
__device__ __forceinline__ float bf2f(unsigned short h) {
  union { unsigned int u; float f; } v; v.u = ((unsigned int)h) << 16;
  return v.f;
}
__device__ __forceinline__ float fast_tanh(float x) {
  float e = __expf(2.f * x);
  return 1.f - 2.f / (e + 1.f);
}
__device__ __forceinline__ float fast_sigmoid(float x) {
  return 1.f / (1.f + __expf(-x));
}

// ---------------- fused convert: all fp32->bf16 staging in ONE kernel ----------------
#define NSEG 14
#define CHUNK4 2048
struct SegT {
  const float* src;
  unsigned short* dst;
  int n4;
  int nrows;
  int mode;    // 0 plain, 1 pad-rows, 2 timestep-shift
  int blk0;
};
struct SegTable { SegT s[NSEG]; };

__global__ __launch_bounds__(256) void k_convall(SegTable tab) {
  int b = blockIdx.x;
  int si = 0;
#pragma unroll
  for (int i = 1; i < NSEG; ++i) si += (b >= tab.s[i].blk0);
  SegT sg = tab.s[si];
  int lb = b - sg.blk0;
  int end = (lb + 1) * CHUNK4; end = end < sg.n4 ? end : sg.n4;
  for (int i = lb * CHUNK4 + threadIdx.x; i < end; i += 256) {
    ushort4 o; o.x = o.y = o.z = o.w = 0;
    if (sg.mode == 0) {
      float4 v = ((const float4*)sg.src)[i];
      o.x = f2bf(v.x); o.y = f2bf(v.y); o.z = f2bf(v.z); o.w = f2bf(v.w);
    } else if (sg.mode == 1) {
      int row = i / 192;
      if (row < sg.nrows) {
        float4 v = ((const float4*)sg.src)[i];
        o.x = f2bf(v.x); o.y = f2bf(v.y); o.z = f2bf(v.z); o.w = f2bf(v.w);
      }
    } else {
      int bt = i / 192;
      if (bt % TT != 0) {
        float4 v = ((const float4*)sg.src)[i - 192];
        o.x = f2bf(v.x); o.y = f2bf(v.y); o.z = f2bf(v.z); o.w = f2bf(v.w);
      }
    }
    ((ushort4*)sg.dst)[i] = o;
  }
}

// ---------------- k_xmean: xm[b,c] = bf16(mean_t x[b,t,c]) ----------------
__global__ __launch_bounds__(256) void k_xmean(const float* __restrict__ x,
                                               unsigned short* __restrict__ xm) {
  int b = blockIdx.x / 6;
  int c = (blockIdx.x % 6) * 256 + threadIdx.x;
  float s = 0.f;
  for (int t = 0; t < TT; ++t) s += x[((size_t)b * TT + t) * E2 + c];
  xm[(size_t)b * E2 + c] = f2bf(s * (1.f / 60.f));
}

// ---------------- segmented 128^2 2-phase GEMM (skinny N=64 GEMMs) ----------------
struct SSeg {
  const unsigned short* A; const unsigned short* B; float* C;
  int M, Nout, K, nMblk, blk0;
};
#define NSSEG 3
struct SSegTable { SSeg s[NSSEG]; };

__global__ __launch_bounds__(256) void gemm_bt_seg(SSegTable tab)
{
  __shared__ __attribute__((aligned(16))) unsigned short As[128*32];
  __shared__ __attribute__((aligned(16))) unsigned short Bs[128*32];
  const int tid  = threadIdx.x;
  const int lane = tid & 63;
  const int wave = tid >> 6;

  const int nwg = gridDim.x;
  const int id  = blockIdx.x;
  const int q = nwg >> 3, r = nwg & 7;
  const int xcd = id & 7, lo = id >> 3;
  const int wgid = (xcd < r ? xcd * (q + 1) : r * (q + 1) + (xcd - r) * q) + lo;

  int si = 0;
#pragma unroll
  for (int i = 1; i < NSSEG; ++i) si += (wgid >= tab.s[i].blk0);
  const SSeg sg = tab.s[si];
  const int lwg = wgid - sg.blk0;
  const int mb = lwg % sg.nMblk;
  const int nb = lwg / sg.nMblk;
  const int M = sg.M, Nout = sg.Nout, K = sg.K;
  const unsigned short* __restrict__ A  = sg.A;
  const unsigned short* __restrict__ Bw = sg.B;
  float* __restrict__ C = sg.C;
  const int m0 = mb * 128;
  const int n0 = nb * 128;
  const int wm = (wave >> 1) * 64;
  const int wn = (wave & 1) * 64;

  f32x4 acc[4][4];
#pragma unroll
  for (int i = 0; i < 4; ++i)
#pragma unroll
    for (int j = 0; j < 4; ++j) acc[i][j] = f32x4{0.f, 0.f, 0.f, 0.f};

  const int lrow = lane & 15;
  const int kb   = (lane >> 4) * 8;

  for (int k0 = 0; k0 < K; k0 += 32) {
    __syncthreads();
#pragma unroll
    for (int p = 0; p < 2; ++p) {
      int slot = p * 256 + wave * 64 + lane;
      int row = slot >> 2, c8 = slot & 3;
      int ar = m0 + row; ar = ar < M ? ar : (M - 1);
      const unsigned short* asrc = A + (size_t)ar * K + k0 + c8 * 8;
      __builtin_amdgcn_global_load_lds(
          (const __attribute__((address_space(1))) void*)asrc,
          (__attribute__((address_space(3))) void*)&As[(p * 256 + wave * 64) * 8],
          16, 0, 0);
      const unsigned short* bsrc = Bw + (size_t)(n0 + row) * K + k0 + c8 * 8;
      __builtin_amdgcn_global_load_lds(
          (const __attribute__((address_space(1))) void*)bsrc,
          (__attribute__((address_space(3))) void*)&Bs[(p * 256 + wave * 64) * 8],
          16, 0, 0);
    }
    __syncthreads();

    bf16x8 av[4], bv[4];
#pragma unroll
    for (int i = 0; i < 4; ++i)
      av[i] = *(const bf16x8*)&As[(wm + i * 16 + lrow) * 32 + kb];
#pragma unroll
    for (int j = 0; j < 4; ++j)
      bv[j] = *(const bf16x8*)&Bs[(wn + j * 16 + lrow) * 32 + kb];
#pragma unroll
    for (int i = 0; i < 4; ++i)
#pragma unroll
      for (int j = 0; j < 4; ++j)
        acc[i][j] = __builtin_amdgcn_mfma_f32_16x16x32_bf16(av[i], bv[j], acc[i][j], 0, 0, 0);
  }

  const int cr = (lane >> 4) * 4;
  const int cc = lane & 15;
#pragma unroll
  for (int i = 0; i < 4; ++i) {
    int row0 = m0 + wm + i * 16 + cr;
#pragma unroll
    for (int j = 0; j < 4; ++j) {
      int col = n0 + wn + j * 16 + cc;
      if (col < Nout) {
#pragma unroll
        for (int r2 = 0; r2 < 4; ++r2) {
          int row = row0 + r2;
          if (row < M) C[(size_t)row * Nout + col] = acc[i][j][r2];
        }
      }
    }
  }
}

// ---------------- 256^2 pipelined GEMM: BK=32, 3-buffer, lean 2-phase/tile ----------------
// Tile kt uses buf kt%3; during tile kt we stage tile kt+2 into buf (kt+2)%3.
// VM4 at each tile end provably drains tile kt+1's loads (correct-by-construction
// arrival gate); ONE closing barrier per phase (dead-panel writes need no pre-barrier).
// Fragment ds_reads are compiler-visible loads (fine-grained lgkmcnt auto-emitted).
// Swizzle (both-sides, rule #21): 16B-slot s' = s ^ ((row>>1)&3) on stage SOURCE
// and on ds_read address. LDS: 3 bufs x (A 16KB @ +0, B 16KB @ +16384) = 96KB.
#define BARR() do { asm volatile("" ::: "memory"); __builtin_amdgcn_s_barrier(); \
                    asm volatile("" ::: "memory"); } while (0)
#define VM4() asm volatile("s_waitcnt vmcnt(4)" ::: "memory")
#define VM0() asm volatile("s_waitcnt vmcnt(0)" ::: "memory")

// one stage unit = one 256x32 bf16 panel (A or B) = 2 gload_lds x 512 threads
#define STAGE1(bufi, op, kt) do {                                               \
  int k0_ = (kt) * 32;                                                          \
  _Pragma("unroll")                                                             \
  for (int l_ = 0; l_ < 2; ++l_) {                                              \
    int rr_ = l_ * 128 + sr0;                                                   \
    int ss_ = ssp ^ ((rr_ >> 1) & 3);                                           \
    int gr_;                                                                    \
    if (op) gr_ = n0 + rr_;                                                     \
    else    gr_ = CLAMP ? ((m0 + rr_) < M ? (m0 + rr_) : (M - 1)) : (m0 + rr_); \
    const unsigned short* src_ = ((op) ? Bw : Ap) + (size_t)gr_ * K + k0_ + ss_ * 8; \
    char* dst_ = smem + (bufi) * 32768 + (op) * 16384 + l_ * 8192 + w * 1024;   \
    __builtin_amdgcn_global_load_lds(                                           \
        (const __attribute__((address_space(1))) void*)src_,                    \
        (__attribute__((address_space(3))) void*)dst_, 16, 0, 0);               \
  }                                                                             \
} while (0)

#define LDA(bufi, row) (*(const bf16x8*)(smem + (bufi) * 32768 + (row) * 64 + (cg ^ (((row) >> 1) & 3)) * 16))
#define LDB(bufi, row) (*(const bf16x8*)(smem + (bufi) * 32768 + 16384 + (row) * 64 + (cg ^ (((row) >> 1) & 3)) * 16))

// phase JH0: reads A-frags + B n-frags 0,1; MFMA into acc[][0..1]
#define PH0(bufi, STAGE_STMT) do {                                              \
  STAGE_STMT;                                                                   \
  bfr0 = LDB(bufi, wn + lrow);                                                  \
  bfr1 = LDB(bufi, wn + 16 + lrow);                                             \
  _Pragma("unroll")                                                             \
  for (int i_ = 0; i_ < 8; ++i_) afr[i_] = LDA(bufi, wm + i_ * 16 + lrow);      \
  __builtin_amdgcn_s_setprio(1);                                                \
  _Pragma("unroll")                                                             \
  for (int i_ = 0; i_ < 8; ++i_) {                                              \
    acc[i_][0] = __builtin_amdgcn_mfma_f32_16x16x32_bf16(afr[i_], bfr0, acc[i_][0], 0, 0, 0); \
    acc[i_][1] = __builtin_amdgcn_mfma_f32_16x16x32_bf16(afr[i_], bfr1, acc[i_][1], 0, 0, 0); \
  }                                                                             \
  __builtin_amdgcn_s_setprio(0);                                                \
  BARR();                                                                       \
} while (0)

// phase JH1: reads B n-frags 2,3 (A-frags register-carried); MFMA into acc[][2..3]
#define PH1(bufi, STAGE_STMT, VM_STMT) do {                                     \
  STAGE_STMT;                                                                   \
  bfr0 = LDB(bufi, wn + 32 + lrow);                                             \
  bfr1 = LDB(bufi, wn + 48 + lrow);                                             \
  __builtin_amdgcn_s_setprio(1);                                                \
  _Pragma("unroll")                                                             \
  for (int i_ = 0; i_ < 8; ++i_) {                                              \
    acc[i_][2] = __builtin_amdgcn_mfma_f32_16x16x32_bf16(afr[i_], bfr0, acc[i_][2], 0, 0, 0); \
    acc[i_][3] = __builtin_amdgcn_mfma_f32_16x16x32_bf16(afr[i_], bfr1, acc[i_][3], 0, 0, 0); \
  }                                                                             \
  __builtin_amdgcn_s_setprio(0);                                                \
  VM_STMT;                                                                      \
  BARR();                                                                       \
} while (0)

struct GSeg {
  const unsigned short* A; const unsigned short* B; float* C;
  const float* bias;
  int M, Nout, K, nMblk, blk0;
};
#define NGSEG 5
struct GSegTable { GSeg s[NGSEG]; };

template <bool CLAMP>
__global__ __launch_bounds__(512, 2) void gemm8p(GSegTable tab)
{
  extern __shared__ char smem[];
  const int tid  = threadIdx.x;
  const int lane = tid & 63;
  const int w    = tid >> 6;
  const int lrow = lane & 15;
  const int cg   = lane >> 4;             // logical 16B slot
  const int sr0  = w * 16 + (lane >> 2);  // stage row (l_=0)
  const int ssp  = lane & 3;              // physical 16B slot

  const int nwg = gridDim.x;
  const int id  = blockIdx.x;
  const int q = nwg >> 3, r = nwg & 7;
  const int xcd = id & 7, lo = id >> 3;
  const int wgid = (xcd < r ? xcd * (q + 1) : r * (q + 1) + (xcd - r) * q) + lo;

  int si = 0;
#pragma unroll
  for (int i = 1; i < NGSEG; ++i) si += (wgid >= tab.s[i].blk0);
  const GSeg sg = tab.s[si];
  const int lwg = wgid - sg.blk0;
  const int mb = lwg % sg.nMblk;
  const int nb = lwg / sg.nMblk;
  const int M = sg.M, Nout = sg.Nout, K = sg.K;
  const unsigned short* __restrict__ Ap = sg.A;
  const unsigned short* __restrict__ Bw = sg.B;
  float* __restrict__ C = sg.C;
  const float* __restrict__ bias = sg.bias;

  const int m0 = mb * 256;
  const int n0 = nb * 256;
  const int wm = (w >> 2) * 128;
  const int wn = (w & 3) * 64;

  f32x4 acc[8][4];
#pragma unroll
  for (int i = 0; i < 8; ++i)
#pragma unroll
    for (int j = 0; j < 4; ++j) acc[i][j] = f32x4{0.f, 0.f, 0.f, 0.f};
  bf16x8 afr[8];
  bf16x8 bfr0, bfr1;

  const int NT = K >> 5;  // K/32, >= 2

  // prologue: stage tiles 0 and 1; VM4 -> tile0 fully arrived; barrier
  STAGE1(0, 0, 0);
  STAGE1(0, 1, 0);
  STAGE1(1, 0, 1);
  STAGE1(1, 1, 1);
  VM4();
  BARR();

  int b = 0;
  for (int kt = 0; kt < NT - 2; ++kt) {
    int b2 = b + 2; if (b2 >= 3) b2 -= 3;
    PH0(b, STAGE1(b2, 0, kt + 2));
    PH1(b, STAGE1(b2, 1, kt + 2), VM4(););   // drains tile kt+1's 4 loads
    ++b; if (b == 3) b = 0;
  }
  // kt = NT-2: no staging; VM0 drains tile NT-1's loads
  PH0(b, ;);
  PH1(b, ;, VM0(););
  ++b; if (b == 3) b = 0;
  // kt = NT-1
  PH0(b, ;);
  {
    bfr0 = LDB(b, wn + 32 + lrow);
    bfr1 = LDB(b, wn + 48 + lrow);
#pragma unroll
    for (int i_ = 0; i_ < 8; ++i_) {
      acc[i_][2] = __builtin_amdgcn_mfma_f32_16x16x32_bf16(afr[i_], bfr0, acc[i_][2], 0, 0, 0);
      acc[i_][3] = __builtin_amdgcn_mfma_f32_16x16x32_bf16(afr[i_], bfr1, acc[i_][3], 0, 0, 0);
    }
  }

  // epilogue: C/D layout col=lane&15, row=(lane>>4)*4+reg
#pragma unroll
  for (int i = 0; i < 8; ++i) {
    int row0 = m0 + wm + i * 16 + (lane >> 4) * 4;
#pragma unroll
    for (int j = 0; j < 4; ++j) {
      int col = n0 + wn + j * 16 + (lane & 15);
      if (col < Nout) {
        float badd = bias ? bias[col] : 0.f;
#pragma unroll
        for (int r2 = 0; r2 < 4; ++r2) {
          int row = row0 + r2;
          if (!CLAMP || row < M) C[(size_t)row * Nout + col] = acc[i][j][r2] + badd;
        }
      }
    }
  }
}

// ---------------- E2: s_t = sigmoid(xs + hs) * tanh(cells) -> bf16 ----------------
__global__ void k_st(const float* __restrict__ XS, const float* __restrict__ HS,
                     const float* __restrict__ cells, unsigned short* __restrict__ stbf, int n) {
  int i = blockIdx.x * blockDim.x + threadIdx.x;
  int stride = gridDim.x * blockDim.x;
  for (; i < n; i += stride) {
    float pre = XS[i] + HS[i];
    float v = fast_sigmoid(pre) * fast_tanh(cells[i]);
    stbf[i] = f2bf(v);
  }
}

// ---------------- E3: switch softmax + V ----------------
__global__ __launch_bounds__(256) void k_switch(
    const float* __restrict__ AH, const float* __restrict__ AG,
    const float* __restrict__ q, const float* __restrict__ wsw,
    const float* __restrict__ H, const float* __restrict__ G,
    unsigned short* __restrict__ Vbf, float* __restrict__ sw_out)
{
  int bl = blockIdx.x;
  int b = bl / LL;
  int tid = threadIdx.x;
  float aH = 0.f, aG = 0.f;
  for (int h = tid; h < HID; h += 256) {
    float qv = q[b * HID + h], w = wsw[h];
    aH += fast_tanh(AH[(size_t)bl * HID + h] + qv) * w;
    aG += fast_tanh(AG[(size_t)bl * HID + h] + qv) * w;
  }
#pragma unroll
  for (int off = 32; off > 0; off >>= 1) {
    aH += __shfl_down(aH, off);
    aG += __shfl_down(aG, off);
  }
  __shared__ float redH[4], redG[4];
  int lane = tid & 63, wave = tid >> 6;
  if (lane == 0) { redH[wave] = aH; redG[wave] = aG; }
  __syncthreads();
  float sH = redH[0] + redH[1] + redH[2] + redH[3];
  float sG = redG[0] + redG[1] + redG[2] + redG[3];
  float m = fmaxf(sH, sG);
  float e0 = __expf(sH - m), e1 = __expf(sG - m);
  float inv = 1.f / (e0 + e1);
  float sw0 = e0 * inv, sw1 = e1 * inv;
  if (tid == 0) { sw_out[bl * 2] = sw0; sw_out[bl * 2 + 1] = sw1; }
  for (int h = tid; h < HID; h += 256) {
    float v = sw0 * H[(size_t)bl * HID + h] + sw1 * G[(size_t)bl * HID + h];
    Vbf[(size_t)bl * HID + h] = f2bf(v);
  }
}

// ---------------- E4: z_t/z_s -> alpha/beta -> c_hat+hiddens ----------------
__global__ __launch_bounds__(256) void k_attn(
    const float* __restrict__ PV, const float* __restrict__ PG,
    const float* __restrict__ SS, const float* __restrict__ wh,
    const unsigned short* __restrict__ stbf, const unsigned short* __restrict__ Vbf,
    const float* __restrict__ hiddens,
    float* __restrict__ alpha_out, float* __restrict__ beta_out,
    unsigned short* __restrict__ chh)
{
  const int TG = 4;
  int b  = blockIdx.x / (TT / TG);
  int t0 = (blockIdx.x % (TT / TG)) * TG;
  int tid = threadIdx.x;
  __shared__ float pg_s[TG][LL], wh_s[LL], zz[TG][LL + 1], alpha_s[TG][LL], beta_sh[TG];

  if (tid < LL) wh_s[tid] = wh[tid];
  if (tid < TG * LL) {
    int tt = tid / LL, k = tid - tt * LL;
    pg_s[tt][k] = PG[(size_t)(b * TT + t0 + tt) * 64 + k];
  }
  __syncthreads();

  if (tid < TG * (LL + 1)) {
    int tt = tid / (LL + 1), l = tid - tt * (LL + 1);
    const float* src = (l < LL) ? &PV[((size_t)b * LL + l) * 64]
                                : &SS[(size_t)(b * TT + t0 + tt) * 64];
    float acc = 0.f;
    for (int k = 0; k < LL; ++k) acc += fast_tanh(src[k] + pg_s[tt][k]) * wh_s[k];
    zz[tt][l] = acc;
  }
  __syncthreads();

  if (tid < TG) {
    int tt = tid, bt = b * TT + t0 + tt;
    float mx = -1e30f;
    for (int l = 0; l < LL; ++l) mx = fmaxf(mx, zz[tt][l]);
    float sum = 0.f;
    for (int l = 0; l < LL; ++l) { float e = __expf(zz[tt][l] - mx); alpha_s[tt][l] = e; sum += e; }
    float inv = 1.f / sum;
    for (int l = 0; l < LL; ++l) {
      alpha_s[tt][l] *= inv;
      alpha_out[(size_t)bt * LL + l] = alpha_s[tt][l];
    }
    float mx2 = fmaxf(mx, zz[tt][LL]);
    float s2 = 0.f;
    for (int l = 0; l <= LL; ++l) s2 += __expf(zz[tt][l] - mx2);
    float bet = __expf(zz[tt][LL] - mx2) / s2;
    beta_sh[tt] = bet;
    beta_out[bt] = bet;
  }
  __syncthreads();

  for (int h = tid; h < HID; h += 256) {
    float ct[TG] = {0.f, 0.f, 0.f, 0.f};
    for (int l = 0; l < LL; ++l) {
      float v = bf2f(Vbf[((size_t)b * LL + l) * HID + h]);
#pragma unroll
      for (int tt = 0; tt < TG; ++tt) ct[tt] += alpha_s[tt][l] * v;
    }
#pragma unroll
    for (int tt = 0; tt < TG; ++tt) {
      int bt = b * TT + t0 + tt;
      float bet = beta_sh[tt];
      float s = bf2f(stbf[(size_t)bt * HID + h]);
      float chat = bet * s + (1.f - bet) * ct[tt];
      chh[(size_t)bt * HID + h] = f2bf(chat + hiddens[(size_t)bt * HID + h]);
    }
  }
}

// ---------------- launcher ----------------
static inline int nblk(long n) {
  long g = (n + 255) / 256;
  if (g > 8192) g = 8192;
  return (int)g;
}

extern "C" void kernel_launch(void* const* d_in, const int* in_sizes, int n_in,
                              void* d_out, int out_size, void* d_ws, size_t ws_size,
                              hipStream_t stream)
{
  const float* x       = (const float*)d_in[0];
  const float* hiddens = (const float*)d_in[1];
  const float* cells   = (const float*)d_in[2];
  const float* G       = (const float*)d_in[3];
  const float* H       = (const float*)d_in[4];
  const float* W_sx    = (const float*)d_in[5];
  const float* W_sh    = (const float*)d_in[6];
  const float* W_ax    = (const float*)d_in[7];
  const float* W_ah    = (const float*)d_in[8];
  const float* W_ag    = (const float*)d_in[9];
  const float* w_sw    = (const float*)d_in[10];
  const float* Wv      = (const float*)d_in[11];
  const float* Wg      = (const float*)d_in[12];
  const float* Ws      = (const float*)d_in[13];
  const float* wh      = (const float*)d_in[14];
  const float* W_mlp   = (const float*)d_in[15];
  const float* b_mlp   = (const float*)d_in[16];

  float* scores = (float*)d_out;
  float* alpha  = scores + (size_t)BT * VOC;
  float* beta   = alpha + (size_t)BT * LL;
  float* swout  = beta + BT;

  char* wsp = (char*)d_ws;
  size_t off = 0;
  auto alloc = [&](size_t bytes) -> char* {
    char* p = wsp + off;
    off += (bytes + 255) & ~(size_t)255;
    return p;
  };

  unsigned short* xbf    = (unsigned short*)alloc((size_t)BT * E2 * 2);
  unsigned short* wsa    = (unsigned short*)alloc((size_t)E2 * E2 * 2);  // [W_sx; W_ax]
  unsigned short* hprev  = (unsigned short*)alloc((size_t)BT * HID * 2);
  unsigned short* wshb   = (unsigned short*)alloc((size_t)HID * HID * 2);
  unsigned short* wahb   = (unsigned short*)alloc((size_t)HID * HID * 2);
  unsigned short* wagb   = (unsigned short*)alloc((size_t)HID * HID * 2);
  unsigned short* Hbf    = (unsigned short*)alloc((size_t)BL * HID * 2);
  unsigned short* Gbf    = (unsigned short*)alloc((size_t)BL * HID * 2);
  unsigned short* hidbf  = (unsigned short*)alloc((size_t)BT * HID * 2);
  unsigned short* wvb    = (unsigned short*)alloc((size_t)NPAD_S * HID * 2);
  unsigned short* wgb    = (unsigned short*)alloc((size_t)NPAD_S * HID * 2);
  unsigned short* wsb    = (unsigned short*)alloc((size_t)NPAD_S * HID * 2);
  unsigned short* wmlpb  = (unsigned short*)alloc((size_t)NPAD_MLP * HID * 2);
  unsigned short* Vbf    = (unsigned short*)alloc((size_t)BL * HID * 2);
  unsigned short* stbf   = (unsigned short*)alloc((size_t)BT * HID * 2);
  unsigned short* chh    = (unsigned short*)alloc((size_t)BT * HID * 2);
  unsigned short* xmbf   = (unsigned short*)alloc((size_t)BB * E2 * 2);
  float* XS = (float*)alloc((size_t)BT * HID * 4);
  float* HS = (float*)alloc((size_t)BT * HID * 4);
  float* AH = (float*)alloc((size_t)BL * HID * 4);
  float* AG = (float*)alloc((size_t)BL * HID * 4);
  float* qb = (float*)alloc((size_t)BB * HID * 4);
  float* PV = (float*)alloc((size_t)BL * 64 * 4);
  float* PG = (float*)alloc((size_t)BT * 64 * 4);
  float* SS = (float*)alloc((size_t)BT * 64 * 4);
  (void)ws_size; (void)in_sizes; (void)n_in; (void)out_size;

  // --- 1: fused converts ---
  SegTable tab;
  int blk = 0, si = 0;
  auto seg = [&](const float* s, unsigned short* d, int n4, int nrows, int mode) {
    tab.s[si].src = s; tab.s[si].dst = d; tab.s[si].n4 = n4;
    tab.s[si].nrows = nrows; tab.s[si].mode = mode; tab.s[si].blk0 = blk;
    blk += (n4 + CHUNK4 - 1) / CHUNK4; ++si;
  };
  seg(W_sx, wsa,                        HID * E2 / 4, 0, 0);
  seg(W_ax, wsa + (size_t)HID * E2,     HID * E2 / 4, 0, 0);
  seg(x, xbf,                           BT * E2 / 4, 0, 0);
  seg(hiddens, hprev,                   BT * HID / 4, 0, 2);
  seg(W_sh, wshb,                       HID * HID / 4, 0, 0);
  seg(W_ah, wahb,                       HID * HID / 4, 0, 0);
  seg(W_ag, wagb,                       HID * HID / 4, 0, 0);
  seg(H, Hbf,                           BL * HID / 4, 0, 0);
  seg(G, Gbf,                           BL * HID / 4, 0, 0);
  seg(hiddens, hidbf,                   BT * HID / 4, 0, 0);
  seg(Wv, wvb,                          NPAD_S * HID / 4, LL, 1);
  seg(Wg, wgb,                          NPAD_S * HID / 4, LL, 1);
  seg(Ws, wsb,                          NPAD_S * HID / 4, LL, 1);
  seg(W_mlp, wmlpb,                     NPAD_MLP * HID / 4, VOC, 1);
  k_convall<<<blk, 256, 0, stream>>>(tab);

  // --- 2: x time-mean (for q) ---
  k_xmean<<<BB * 6, 256, 0, stream>>>(x, xmbf);

  // --- 3: mega pipelined GEMM dispatch: xs, sh, ah, ag, q (CLAMP=true) ---
  GSegTable gt;
  int gblk = 0, gi = 0;
  auto gseg = [&](const unsigned short* A, const unsigned short* B, float* C,
                  const float* bias, int M, int N, int K, int nMblk, int nNblk) {
    gt.s[gi].A = A; gt.s[gi].B = B; gt.s[gi].C = C; gt.s[gi].bias = bias;
    gt.s[gi].M = M; gt.s[gi].Nout = N; gt.s[gi].K = K; gt.s[gi].nMblk = nMblk;
    gt.s[gi].blk0 = gblk;
    gblk += nMblk * nNblk; ++gi;
  };
  gseg(xbf,   wsa,                      XS, nullptr, BT, HID, E2,  15, 3);
  gseg(hprev, wshb,                     HS, nullptr, BT, HID, HID, 15, 3);
  gseg(Hbf,   wahb,                     AH, nullptr, BL, HID, HID, 13, 3);
  gseg(Gbf,   wagb,                     AG, nullptr, BL, HID, HID, 13, 3);
  gseg(xmbf,  wsa + (size_t)HID * E2,   qb, nullptr, BB, HID, E2,  1,  3);
  gemm8p<true><<<gblk, 512, 98304, stream>>>(gt);

  // --- 4/5: gate + switch ---
  k_st<<<nblk((long)BT * HID), 256, 0, stream>>>(XS, HS, cells, stbf, BT * HID);
  k_switch<<<BL, 256, 0, stream>>>(AH, AG, qb, w_sw, H, G, Vbf, swout);

  // --- 6: skinny GEMMs (one segmented dispatch) ---
  SSegTable st;
  st.s[0] = SSeg{Vbf,   wvb, PV, BL, 64, HID, 25, 0};
  st.s[1] = SSeg{hidbf, wgb, PG, BT, 64, HID, 30, 25};
  st.s[2] = SSeg{stbf,  wsb, SS, BT, 64, HID, 30, 55};
  gemm_bt_seg<<<85, 256, 0, stream>>>(st);

  // --- 7: attention epilogue ---
  k_attn<<<BB * (TT / 4), 256, 0, stream>>>(PV, PG, SS, wh, stbf, Vbf, hiddens,
                                            alpha, beta, chh);

  // --- 8: scores GEMM (CLAMP=false: 3840 = 15*256 exact; +bias), grid 600 ---
  GSegTable gs;
  for (int i = 0; i < NGSEG; ++i) { gs.s[i].blk0 = 0x7fffffff; gs.s[i].A = chh; gs.s[i].B = wmlpb; gs.s[i].C = scores; gs.s[i].bias = b_mlp; gs.s[i].M = BT; gs.s[i].Nout = VOC; gs.s[i].K = HID; gs.s[i].nMblk = 15; }
  gs.s[0].blk0 = 0;
  gemm8p<false><<<15 * 40, 512, 98304, stream>>>(gs);
}